// Round 5
// baseline (1961.472 us; speedup 1.0000x reference)
//
#include <hip/hip_runtime.h>
#include <hip/hip_bf16.h>

// ---------------------------------------------------------------------------
// f32 GEMM, "NT" layout: C[M,N] = A[M,K] * B[N,K]^T (+bias) (optional relu)
// Both operands are K-contiguous (row-major), which matches x@W.T and hn@hn.T.
// 128x128 block tile, 256 threads, 8x8 per-thread micro-tile, K-step 16.
// ---------------------------------------------------------------------------
__global__ __launch_bounds__(256)
void gemm_nt(const float* __restrict__ A, const float* __restrict__ B,
             const float* __restrict__ bias, float* __restrict__ C,
             int M, int N, int K, int do_relu)
{
    constexpr int KS = 16;
    constexpr int LDT = 132;   // padded LDS stride (floats)
    __shared__ float As[KS * LDT];
    __shared__ float Bs[KS * LDT];

    const int t    = threadIdx.x;
    const int row0 = blockIdx.y * 128;
    const int col0 = blockIdx.x * 128;
    const int tm   = t & 15;       // C-row group
    const int tn   = t >> 4;       // C-col group
    const int lrow = t >> 2;       // 0..63 staging row
    const int lk   = (t & 3) << 2; // 0,4,8,12 staging k

    const float* Ap0 = A + (size_t)(row0 + lrow)      * K + lk;
    const float* Ap1 = A + (size_t)(row0 + lrow + 64) * K + lk;
    const float* Bp0 = B + (size_t)(col0 + lrow)      * K + lk;
    const float* Bp1 = B + (size_t)(col0 + lrow + 64) * K + lk;

    float acc[8][8];
#pragma unroll
    for (int i = 0; i < 8; ++i)
#pragma unroll
        for (int j = 0; j < 8; ++j) acc[i][j] = 0.f;

    for (int k0 = 0; k0 < K; k0 += KS) {
        const float4 a0 = *(const float4*)(Ap0 + k0);
        const float4 a1 = *(const float4*)(Ap1 + k0);
        const float4 b0 = *(const float4*)(Bp0 + k0);
        const float4 b1 = *(const float4*)(Bp1 + k0);
        __syncthreads();   // previous iteration's consumers done
        As[(lk + 0) * LDT + lrow] = a0.x;
        As[(lk + 1) * LDT + lrow] = a0.y;
        As[(lk + 2) * LDT + lrow] = a0.z;
        As[(lk + 3) * LDT + lrow] = a0.w;
        As[(lk + 0) * LDT + lrow + 64] = a1.x;
        As[(lk + 1) * LDT + lrow + 64] = a1.y;
        As[(lk + 2) * LDT + lrow + 64] = a1.z;
        As[(lk + 3) * LDT + lrow + 64] = a1.w;
        Bs[(lk + 0) * LDT + lrow] = b0.x;
        Bs[(lk + 1) * LDT + lrow] = b0.y;
        Bs[(lk + 2) * LDT + lrow] = b0.z;
        Bs[(lk + 3) * LDT + lrow] = b0.w;
        Bs[(lk + 0) * LDT + lrow + 64] = b1.x;
        Bs[(lk + 1) * LDT + lrow + 64] = b1.y;
        Bs[(lk + 2) * LDT + lrow + 64] = b1.z;
        Bs[(lk + 3) * LDT + lrow + 64] = b1.w;
        __syncthreads();
#pragma unroll
        for (int kk = 0; kk < KS; ++kk) {
            const float4 av0 = *(const float4*)&As[kk * LDT + 8 * tm];
            const float4 av1 = *(const float4*)&As[kk * LDT + 8 * tm + 4];
            const float4 bv0 = *(const float4*)&Bs[kk * LDT + 8 * tn];
            const float4 bv1 = *(const float4*)&Bs[kk * LDT + 8 * tn + 4];
            const float a[8] = {av0.x, av0.y, av0.z, av0.w, av1.x, av1.y, av1.z, av1.w};
            const float bb[8] = {bv0.x, bv0.y, bv0.z, bv0.w, bv1.x, bv1.y, bv1.z, bv1.w};
#pragma unroll
            for (int i = 0; i < 8; ++i)
#pragma unroll
                for (int j = 0; j < 8; ++j)
                    acc[i][j] += a[i] * bb[j];
        }
    }

#pragma unroll
    for (int i = 0; i < 8; ++i) {
        const int r = row0 + 8 * tm + i;
        float* Crow = C + (size_t)r * N + col0 + 8 * tn;
        float o[8];
#pragma unroll
        for (int j = 0; j < 8; ++j) o[j] = acc[i][j];
        if (bias) {
#pragma unroll
            for (int j = 0; j < 8; ++j) o[j] += bias[col0 + 8 * tn + j];
        }
        if (do_relu) {
#pragma unroll
            for (int j = 0; j < 8; ++j) o[j] = fmaxf(o[j], 0.f);
        }
        float4 o0 = {o[0], o[1], o[2], o[3]};
        float4 o1 = {o[4], o[5], o[6], o[7]};
        *(float4*)(Crow)     = o0;
        *(float4*)(Crow + 4) = o1;
    }
}

// ---------------------------------------------------------------------------
// Row L2-normalize: out = in / max(||in||, 1e-12). One block (128 thr) per row.
// ---------------------------------------------------------------------------
__global__ __launch_bounds__(128)
void rownorm(const float* __restrict__ in, float* __restrict__ out)
{
    __shared__ float s[2];
    const int r = blockIdx.x, t = threadIdx.x;
    const float4 v = ((const float4*)(in + (size_t)r * 512))[t];
    float ss = v.x * v.x + v.y * v.y + v.z * v.z + v.w * v.w;
#pragma unroll
    for (int off = 32; off; off >>= 1) ss += __shfl_down(ss, off);
    if ((t & 63) == 0) s[t >> 6] = ss;
    __syncthreads();
    const float den = fmaxf(sqrtf(s[0] + s[1]), 1e-12f);
    float4 o;
    o.x = v.x / den; o.y = v.y / den; o.z = v.z / den; o.w = v.w / den;
    ((float4*)(out + (size_t)r * 512))[t] = o;
}

// ---------------------------------------------------------------------------
// In-place per-row top-31 (jax.lax.top_k semantics: ties -> lowest index) +
// relu on the f32 sim matrix. One block (256 thr) per row; each block owns
// its row exclusively (sim GEMM completed at kernel boundary).
//
// Race-free iterative argmax: each thread caches the best (value,index) key
// over its 32 strided elements; 31 rounds of {wave shfl_xor max-reduce ->
// 4-entry LDS combine -> uniform winner -> bitmap mark (single writer) ->
// only the winner's OWNER thread rescans its 32 elements (bitmap-filtered)}.
// rowv is never modified; every shared RW pair is barrier-separated.
// Key = (mono(f) << 32) | (8191 - idx): max => largest value, ties -> lowest
// index, matching jax.lax.top_k's stable selection.
// ---------------------------------------------------------------------------
__device__ __forceinline__ unsigned mono(float f)
{
    unsigned b = __float_as_uint(f);
    return (b & 0x80000000u) ? ~b : (b | 0x80000000u);
}

__global__ __launch_bounds__(256)
void topk_inplace(float* __restrict__ sim)
{
    constexpr int NC = 8192;
    constexpr int KSEL = 31;
    __shared__ float rowv[NC];
    __shared__ unsigned bitmap[NC / 32];
    __shared__ unsigned long long wred[4];

    const int t = threadIdx.x;
    const int lane = t & 63;
    const int wid = t >> 6;
    float* row = sim + (size_t)blockIdx.x * NC;

#pragma unroll
    for (int j = 0; j < 8; ++j) {
        const int i = t + 256 * j;
        ((float4*)rowv)[i] = ((const float4*)row)[i];
    }
    bitmap[t] = 0u;          // NC/32 == 256 == blockDim
    __syncthreads();

    // per-thread best key over its 32 strided elements
    unsigned long long lk = 0ull;
#pragma unroll
    for (int j = 0; j < 32; ++j) {
        const int i = t + 256 * j;
        const unsigned long long key =
            ((unsigned long long)mono(rowv[i]) << 32) | (unsigned)(NC - 1 - i);
        if (key > lk) lk = key;
    }

    for (int it = 0; it < KSEL; ++it) {
        unsigned long long k = lk;
#pragma unroll
        for (int off = 32; off; off >>= 1) {
            const unsigned long long o = __shfl_xor(k, off);
            if (o > k) k = o;
        }
        if (lane == 0) wred[wid] = k;
        __syncthreads();                       // (A) wred visible to all
        unsigned long long gk = wred[0];
        if (wred[1] > gk) gk = wred[1];
        if (wred[2] > gk) gk = wred[2];
        if (wred[3] > gk) gk = wred[3];
        const int idx = (NC - 1) - (int)(unsigned)(gk & 0xFFFFFFFFull);  // uniform
        if (t == 0) bitmap[idx >> 5] |= (1u << (idx & 31));
        __syncthreads();                       // (B) bitmap visible; wred WAR-safe
        if ((idx & 255) == t) {                // owner rescans its 32, excluding flagged
            unsigned long long nk = 0ull;
            for (int j = 0; j < 32; ++j) {
                const int i = t + 256 * j;
                if ((bitmap[i >> 5] >> (i & 31)) & 1u) continue;
                const unsigned long long key =
                    ((unsigned long long)mono(rowv[i]) << 32) | (unsigned)(NC - 1 - i);
                if (key > nk) nk = key;
            }
            lk = nk;
        }
    }
    __syncthreads();

    // write back: keep top-31 (relu'd), zero elsewhere — full f32 row
#pragma unroll
    for (int j = 0; j < 8; ++j) {
        const int i0 = 4 * (t + 256 * j);      // i0 % 4 == 0, same bitmap word
        const unsigned w = bitmap[i0 >> 5];
        float4 v = *(const float4*)&rowv[i0];
        v.x = ((w >> ((i0 + 0) & 31)) & 1u) ? fmaxf(v.x, 0.f) : 0.f;
        v.y = ((w >> ((i0 + 1) & 31)) & 1u) ? fmaxf(v.y, 0.f) : 0.f;
        v.z = ((w >> ((i0 + 2) & 31)) & 1u) ? fmaxf(v.z, 0.f) : 0.f;
        v.w = ((w >> ((i0 + 3) & 31)) & 1u) ? fmaxf(v.w, 0.f) : 0.f;
        *(float4*)&row[i0] = v;
    }
}

// ---------------------------------------------------------------------------
extern "C" void kernel_launch(void* const* d_in, const int* in_sizes, int n_in,
                              void* d_out, int out_size, void* d_ws, size_t ws_size,
                              hipStream_t stream)
{
    const float* x = (const float*)d_in[0];
    const float* W = (const float*)d_in[1];
    const float* b = (const float*)d_in[2];
    float* out = (float*)d_out;               // f32 [8192, 8192] = 268 MB

    const int N = 8192, D = 512;

    // MLP scratch lives in d_out: these bytes are dead before the sim GEMM
    // overwrites the full output (sim GEMM reads only hn, which is in ws).
    float* h1 = out;                          // f32, bytes [0, 16.8MB)
    float* h2 = out + (size_t)N * D;          // f32, bytes [16.8, 33.6MB)
    float* hn = (float*)d_ws;                 // f32, 16.8MB — only ws use

    dim3 tb(256);
    // MLP layer 0 (+relu) and layer 1
    gemm_nt<<<dim3(D / 128, N / 128), tb, 0, stream>>>(x,  W,                 b,     h1, N, D, D, 1);
    gemm_nt<<<dim3(D / 128, N / 128), tb, 0, stream>>>(h1, W + (size_t)D * D, b + D, h2, N, D, D, 0);
    // L2 normalize rows: h2 (d_out scratch) -> hn (ws)
    rownorm<<<N, 128, 0, stream>>>(h2, hn);
    // sim = hn @ hn^T, written directly into d_out (f32, full matrix)
    gemm_nt<<<dim3(N / 128, N / 128), tb, 0, stream>>>(hn, hn, nullptr, out, N, N, D, 0);
    // per-row top-31 + relu, in place
    topk_inplace<<<N, tb, 0, stream>>>(out);
}

// Round 9
// 1440.926 us; speedup vs baseline: 1.3613x; 1.3613x over previous
//
#include <hip/hip_runtime.h>
#include <hip/hip_bf16.h>

// ---------------------------------------------------------------------------
// f32 GEMM, "NT" layout: C[M,N] = A[M,K] * B[N,K]^T (+bias) (optional relu)
// 128x128 block tile, 256 threads, 8x8 per-thread micro-tile, K-step 16.
// Register-prefetch pipeline: tile k0 is written regs->LDS, then tile k0+KS
// is loaded into regs BEFORE the 16-kk compute, hiding global latency under
// the FMA issue stream (previous version stalled on vmcnt(0) every K-step).
// ---------------------------------------------------------------------------
__global__ __launch_bounds__(256)
void gemm_nt(const float* __restrict__ A, const float* __restrict__ B,
             const float* __restrict__ bias, float* __restrict__ C,
             int M, int N, int K, int do_relu)
{
    constexpr int KS = 16;
    constexpr int LDT = 132;   // padded LDS stride (floats)
    __shared__ float As[KS * LDT];
    __shared__ float Bs[KS * LDT];

    const int t    = threadIdx.x;
    const int row0 = blockIdx.y * 128;
    const int col0 = blockIdx.x * 128;
    const int tm   = t & 15;       // C-row group
    const int tn   = t >> 4;       // C-col group
    const int lrow = t >> 2;       // 0..63 staging row
    const int lk   = (t & 3) << 2; // 0,4,8,12 staging k

    const float* Ap0 = A + (size_t)(row0 + lrow)      * K + lk;
    const float* Ap1 = A + (size_t)(row0 + lrow + 64) * K + lk;
    const float* Bp0 = B + (size_t)(col0 + lrow)      * K + lk;
    const float* Bp1 = B + (size_t)(col0 + lrow + 64) * K + lk;

    // prefetch tile 0 into registers
    float4 a0 = *(const float4*)(Ap0);
    float4 a1 = *(const float4*)(Ap1);
    float4 b0 = *(const float4*)(Bp0);
    float4 b1 = *(const float4*)(Bp1);

    float acc[8][8];
#pragma unroll
    for (int i = 0; i < 8; ++i)
#pragma unroll
        for (int j = 0; j < 8; ++j) acc[i][j] = 0.f;

    for (int k0 = 0; k0 < K; k0 += KS) {
        __syncthreads();   // previous iteration's LDS consumers done
        As[(lk + 0) * LDT + lrow] = a0.x;
        As[(lk + 1) * LDT + lrow] = a0.y;
        As[(lk + 2) * LDT + lrow] = a0.z;
        As[(lk + 3) * LDT + lrow] = a0.w;
        As[(lk + 0) * LDT + lrow + 64] = a1.x;
        As[(lk + 1) * LDT + lrow + 64] = a1.y;
        As[(lk + 2) * LDT + lrow + 64] = a1.z;
        As[(lk + 3) * LDT + lrow + 64] = a1.w;
        Bs[(lk + 0) * LDT + lrow] = b0.x;
        Bs[(lk + 1) * LDT + lrow] = b0.y;
        Bs[(lk + 2) * LDT + lrow] = b0.z;
        Bs[(lk + 3) * LDT + lrow] = b0.w;
        Bs[(lk + 0) * LDT + lrow + 64] = b1.x;
        Bs[(lk + 1) * LDT + lrow + 64] = b1.y;
        Bs[(lk + 2) * LDT + lrow + 64] = b1.z;
        Bs[(lk + 3) * LDT + lrow + 64] = b1.w;
        __syncthreads();   // LDS ready
        if (k0 + KS < K) { // issue next-tile loads; latency hides under compute
            a0 = *(const float4*)(Ap0 + k0 + KS);
            a1 = *(const float4*)(Ap1 + k0 + KS);
            b0 = *(const float4*)(Bp0 + k0 + KS);
            b1 = *(const float4*)(Bp1 + k0 + KS);
        }
#pragma unroll
        for (int kk = 0; kk < KS; ++kk) {
            const float4 av0 = *(const float4*)&As[kk * LDT + 8 * tm];
            const float4 av1 = *(const float4*)&As[kk * LDT + 8 * tm + 4];
            const float4 bv0 = *(const float4*)&Bs[kk * LDT + 8 * tn];
            const float4 bv1 = *(const float4*)&Bs[kk * LDT + 8 * tn + 4];
            const float a[8] = {av0.x, av0.y, av0.z, av0.w, av1.x, av1.y, av1.z, av1.w};
            const float bb[8] = {bv0.x, bv0.y, bv0.z, bv0.w, bv1.x, bv1.y, bv1.z, bv1.w};
#pragma unroll
            for (int i = 0; i < 8; ++i)
#pragma unroll
                for (int j = 0; j < 8; ++j)
                    acc[i][j] += a[i] * bb[j];
        }
    }

#pragma unroll
    for (int i = 0; i < 8; ++i) {
        const int r = row0 + 8 * tm + i;
        float* Crow = C + (size_t)r * N + col0 + 8 * tn;
        float o[8];
#pragma unroll
        for (int j = 0; j < 8; ++j) o[j] = acc[i][j];
        if (bias) {
#pragma unroll
            for (int j = 0; j < 8; ++j) o[j] += bias[col0 + 8 * tn + j];
        }
        if (do_relu) {
#pragma unroll
            for (int j = 0; j < 8; ++j) o[j] = fmaxf(o[j], 0.f);
        }
        float4 o0 = {o[0], o[1], o[2], o[3]};
        float4 o1 = {o[4], o[5], o[6], o[7]};
        *(float4*)(Crow)     = o0;
        *(float4*)(Crow + 4) = o1;
    }
}

// ---------------------------------------------------------------------------
// Row L2-normalize: out = in / max(||in||, 1e-12). One block (128 thr) per row.
// ---------------------------------------------------------------------------
__global__ __launch_bounds__(128)
void rownorm(const float* __restrict__ in, float* __restrict__ out)
{
    __shared__ float s[2];
    const int r = blockIdx.x, t = threadIdx.x;
    const float4 v = ((const float4*)(in + (size_t)r * 512))[t];
    float ss = v.x * v.x + v.y * v.y + v.z * v.z + v.w * v.w;
#pragma unroll
    for (int off = 32; off; off >>= 1) ss += __shfl_down(ss, off);
    if ((t & 63) == 0) s[t >> 6] = ss;
    __syncthreads();
    const float den = fmaxf(sqrtf(s[0] + s[1]), 1e-12f);
    float4 o;
    o.x = v.x / den; o.y = v.y / den; o.z = v.z / den; o.w = v.w / den;
    ((float4*)(out + (size_t)r * 512))[t] = o;
}

// ---------------------------------------------------------------------------
// In-place per-row top-31 + relu via RADIX SELECT (jax.lax.top_k semantics:
// ties -> lowest index). One block (256 thr) per row.
//
// 4 passes of 8-bit digits over the monotonic-uint key, MSB first. Race-free:
// sh_pref/sh_targ are DOUBLE-BUFFERED (pass p reads slot p&1, crossing lane
// writes slot (p+1)&1; every shared RW pair separated by the end-of-pass
// barrier). Histogram is PER-WAVE (bins4[wid]) to cut same-address LDS-atomic
// serialization 4x (digits concentrate in ~4 bins for cosine-sim data).
// 256-bin suffix-scan + crossing detection runs entirely in wave 0.
// Ties at the cutoff: accept the m lowest indices (tie list + single thr).
// ---------------------------------------------------------------------------
__device__ __forceinline__ unsigned mono(float f)
{
    unsigned b = __float_as_uint(f);
    return (b & 0x80000000u) ? ~b : (b | 0x80000000u);
}
__device__ __forceinline__ float unmono(unsigned u)
{
    return __uint_as_float((u & 0x80000000u) ? (u ^ 0x80000000u) : ~u);
}

__global__ __launch_bounds__(256)
void topk_radix(float* __restrict__ sim)
{
    constexpr int NC = 8192;
    __shared__ unsigned keys[NC];        // 32 KB: monotonic keys
    __shared__ unsigned bins4[4][256];   // per-wave histograms
    __shared__ unsigned sh_pref[2], sh_targ[2];
    __shared__ int tie_idx[256];
    __shared__ int tie_cnt, sh_tie_thr;

    const int t = threadIdx.x;
    const int lane = t & 63;
    const int wid = t >> 6;
    float* row = sim + (size_t)blockIdx.x * NC;

    if (t == 0) { sh_pref[0] = 0u; sh_targ[0] = 31u; tie_cnt = 0; }
#pragma unroll
    for (int j = 0; j < 8; ++j) {
        const int i0 = 4 * (t + 256 * j);
        const float4 v = *(const float4*)&row[i0];
        uint4 k;
        k.x = mono(v.x); k.y = mono(v.y); k.z = mono(v.z); k.w = mono(v.w);
        *(uint4*)&keys[i0] = k;
    }
    __syncthreads();

    unsigned prefmask = 0u;
    for (int p = 0; p < 4; ++p) {
        const int shift = 24 - 8 * p;
#pragma unroll
        for (int w = 0; w < 4; ++w) bins4[w][t] = 0u;
        __syncthreads();                         // bins zeroed (keys ready, p=0)
        const unsigned prefix = sh_pref[p & 1];  // written pass p-1, barrier-sep
        const unsigned target = sh_targ[p & 1];
        for (int j = 0; j < 32; ++j) {
            const unsigned u = keys[t + 256 * j];
            if ((u & prefmask) == prefix)
                atomicAdd(&bins4[wid][(u >> shift) & 255u], 1u);
        }
        __syncthreads();                         // histogram complete
        if (wid == 0) {
            unsigned bb[4];
#pragma unroll
            for (int jj = 0; jj < 4; ++jj)
                bb[jj] = bins4[0][4 * lane + jj] + bins4[1][4 * lane + jj]
                       + bins4[2][4 * lane + jj] + bins4[3][4 * lane + jj];
            const unsigned tot = bb[0] + bb[1] + bb[2] + bb[3];
            unsigned s = tot;                    // inclusive suffix-scan over lanes
#pragma unroll
            for (int off = 1; off < 64; off <<= 1) {
                const unsigned o = __shfl_down(s, off);
                if (lane + off < 64) s += o;
            }
            unsigned cge[5];                     // cge[j] = #elems digit >= 4*lane+j
            cge[4] = s - tot;
            cge[3] = cge[4] + bb[3];
            cge[2] = cge[3] + bb[2];
            cge[1] = cge[2] + bb[1];
            cge[0] = cge[1] + bb[0];
#pragma unroll
            for (int jj = 0; jj < 4; ++jj) {
                if (cge[jj] >= target && cge[jj + 1] < target) {   // unique crossing
                    sh_pref[(p + 1) & 1] = prefix | ((unsigned)(4 * lane + jj) << shift);
                    sh_targ[(p + 1) & 1] = target - cge[jj + 1];
                }
            }
        }
        prefmask |= (255u << shift);
        __syncthreads();                         // crossing write visible next pass
    }
    const unsigned uc = sh_pref[0];              // exact key of the 31st element
    const int m = (int)sh_targ[0];               // # ties at cutoff to accept

    for (int j = 0; j < 32; ++j) {
        const int i = t + 256 * j;
        if (keys[i] == uc) {
            const int p = atomicAdd(&tie_cnt, 1);
            if (p < 256) tie_idx[p] = i;
        }
    }
    __syncthreads();
    if (t == 0) {
        int n = tie_cnt < 256 ? tie_cnt : 256;
        for (int a = 1; a < n; ++a) {            // tiny insertion sort (n≈1 typ.)
            const int key = tie_idx[a];
            int c = a - 1;
            while (c >= 0 && tie_idx[c] > key) { tie_idx[c + 1] = tie_idx[c]; --c; }
            tie_idx[c + 1] = key;
        }
        const int mm = (m <= n ? m : n);
        sh_tie_thr = tie_idx[mm - 1];            // m-th smallest tie index
    }
    __syncthreads();
    const int tie_thr = sh_tie_thr;

#pragma unroll
    for (int j = 0; j < 8; ++j) {
        const int i0 = 4 * (t + 256 * j);
        const uint4 k = *(const uint4*)&keys[i0];
        float4 v;
        v.x = (k.x > uc || (k.x == uc && i0 + 0 <= tie_thr)) ? fmaxf(unmono(k.x), 0.f) : 0.f;
        v.y = (k.y > uc || (k.y == uc && i0 + 1 <= tie_thr)) ? fmaxf(unmono(k.y), 0.f) : 0.f;
        v.z = (k.z > uc || (k.z == uc && i0 + 2 <= tie_thr)) ? fmaxf(unmono(k.z), 0.f) : 0.f;
        v.w = (k.w > uc || (k.w == uc && i0 + 3 <= tie_thr)) ? fmaxf(unmono(k.w), 0.f) : 0.f;
        *(float4*)&row[i0] = v;
    }
}

// ---------------------------------------------------------------------------
extern "C" void kernel_launch(void* const* d_in, const int* in_sizes, int n_in,
                              void* d_out, int out_size, void* d_ws, size_t ws_size,
                              hipStream_t stream)
{
    const float* x = (const float*)d_in[0];
    const float* W = (const float*)d_in[1];
    const float* b = (const float*)d_in[2];
    float* out = (float*)d_out;               // f32 [8192, 8192] = 268 MB

    const int N = 8192, D = 512;

    // MLP scratch lives in d_out: these bytes are dead before the sim GEMM
    // overwrites the full output (sim GEMM reads only hn, which is in ws).
    float* h1 = out;                          // f32, bytes [0, 16.8MB)
    float* h2 = out + (size_t)N * D;          // f32, bytes [16.8, 33.6MB)
    float* hn = (float*)d_ws;                 // f32, 16.8MB — only ws use

    dim3 tb(256);
    // MLP layer 0 (+relu) and layer 1
    gemm_nt<<<dim3(D / 128, N / 128), tb, 0, stream>>>(x,  W,                 b,     h1, N, D, D, 1);
    gemm_nt<<<dim3(D / 128, N / 128), tb, 0, stream>>>(h1, W + (size_t)D * D, b + D, h2, N, D, D, 0);
    // L2 normalize rows: h2 (d_out scratch) -> hn (ws)
    rownorm<<<N, 128, 0, stream>>>(h2, hn);
    // sim = hn @ hn^T, written directly into d_out (f32, full matrix)
    gemm_nt<<<dim3(N / 128, N / 128), tb, 0, stream>>>(hn, hn, nullptr, out, N, N, D, 0);
    // per-row top-31 + relu, in place (radix select)
    topk_radix<<<N, tb, 0, stream>>>(out);
}

// Round 10
// 1233.197 us; speedup vs baseline: 1.5906x; 1.1684x over previous
//
#include <hip/hip_runtime.h>
#include <hip/hip_bf16.h>

// ---------------------------------------------------------------------------
// f32 GEMM, "NT" layout: C[M,N] = A[M,K] * B[N,K]^T (+bias) (optional relu)
// 128x128 tile, 256 threads, 8x8 micro-tile, K-step 16, register prefetch.
// Used for the two MLP layers (small: 256 blocks).
// ---------------------------------------------------------------------------
__global__ __launch_bounds__(256)
void gemm_nt(const float* __restrict__ A, const float* __restrict__ B,
             const float* __restrict__ bias, float* __restrict__ C,
             int M, int N, int K, int do_relu)
{
    constexpr int KS = 16;
    constexpr int LDT = 132;
    __shared__ float As[KS * LDT];
    __shared__ float Bs[KS * LDT];

    const int t    = threadIdx.x;
    const int row0 = blockIdx.y * 128;
    const int col0 = blockIdx.x * 128;
    const int tm   = t & 15;
    const int tn   = t >> 4;
    const int lrow = t >> 2;
    const int lk   = (t & 3) << 2;

    const float* Ap0 = A + (size_t)(row0 + lrow)      * K + lk;
    const float* Ap1 = A + (size_t)(row0 + lrow + 64) * K + lk;
    const float* Bp0 = B + (size_t)(col0 + lrow)      * K + lk;
    const float* Bp1 = B + (size_t)(col0 + lrow + 64) * K + lk;

    float4 a0 = *(const float4*)(Ap0);
    float4 a1 = *(const float4*)(Ap1);
    float4 b0 = *(const float4*)(Bp0);
    float4 b1 = *(const float4*)(Bp1);

    float acc[8][8];
#pragma unroll
    for (int i = 0; i < 8; ++i)
#pragma unroll
        for (int j = 0; j < 8; ++j) acc[i][j] = 0.f;

    for (int k0 = 0; k0 < K; k0 += KS) {
        __syncthreads();
        As[(lk + 0) * LDT + lrow] = a0.x;
        As[(lk + 1) * LDT + lrow] = a0.y;
        As[(lk + 2) * LDT + lrow] = a0.z;
        As[(lk + 3) * LDT + lrow] = a0.w;
        As[(lk + 0) * LDT + lrow + 64] = a1.x;
        As[(lk + 1) * LDT + lrow + 64] = a1.y;
        As[(lk + 2) * LDT + lrow + 64] = a1.z;
        As[(lk + 3) * LDT + lrow + 64] = a1.w;
        Bs[(lk + 0) * LDT + lrow] = b0.x;
        Bs[(lk + 1) * LDT + lrow] = b0.y;
        Bs[(lk + 2) * LDT + lrow] = b0.z;
        Bs[(lk + 3) * LDT + lrow] = b0.w;
        Bs[(lk + 0) * LDT + lrow + 64] = b1.x;
        Bs[(lk + 1) * LDT + lrow + 64] = b1.y;
        Bs[(lk + 2) * LDT + lrow + 64] = b1.z;
        Bs[(lk + 3) * LDT + lrow + 64] = b1.w;
        __syncthreads();
        if (k0 + KS < K) {
            a0 = *(const float4*)(Ap0 + k0 + KS);
            a1 = *(const float4*)(Ap1 + k0 + KS);
            b0 = *(const float4*)(Bp0 + k0 + KS);
            b1 = *(const float4*)(Bp1 + k0 + KS);
        }
#pragma unroll
        for (int kk = 0; kk < KS; ++kk) {
            const float4 av0 = *(const float4*)&As[kk * LDT + 8 * tm];
            const float4 av1 = *(const float4*)&As[kk * LDT + 8 * tm + 4];
            const float4 bv0 = *(const float4*)&Bs[kk * LDT + 8 * tn];
            const float4 bv1 = *(const float4*)&Bs[kk * LDT + 8 * tn + 4];
            const float a[8] = {av0.x, av0.y, av0.z, av0.w, av1.x, av1.y, av1.z, av1.w};
            const float bb[8] = {bv0.x, bv0.y, bv0.z, bv0.w, bv1.x, bv1.y, bv1.z, bv1.w};
#pragma unroll
            for (int i = 0; i < 8; ++i)
#pragma unroll
                for (int j = 0; j < 8; ++j)
                    acc[i][j] += a[i] * bb[j];
        }
    }

#pragma unroll
    for (int i = 0; i < 8; ++i) {
        const int r = row0 + 8 * tm + i;
        float* Crow = C + (size_t)r * N + col0 + 8 * tn;
        float o[8];
#pragma unroll
        for (int j = 0; j < 8; ++j) o[j] = acc[i][j];
        if (bias) {
#pragma unroll
            for (int j = 0; j < 8; ++j) o[j] += bias[col0 + 8 * tn + j];
        }
        if (do_relu) {
#pragma unroll
            for (int j = 0; j < 8; ++j) o[j] = fmaxf(o[j], 0.f);
        }
        float4 o0 = {o[0], o[1], o[2], o[3]};
        float4 o1 = {o[4], o[5], o[6], o[7]};
        *(float4*)(Crow)     = o0;
        *(float4*)(Crow + 4) = o1;
    }
}

// ---------------------------------------------------------------------------
// SYMMETRIC sim GEMM: C = H * H^T (C is Nn x Nn, H is Nn x K, K-contiguous).
// Only the lower-triangular tile pairs (rt <= ct) are computed: 2080 blocks
// instead of 4096 (2x FLOP cut). Off-diagonal blocks write BOTH the direct
// tile and the mirrored tile; acc columns map to consecutive output columns,
// so the mirror write is also fully-coalesced float4s (no LDS bounce).
// Micro-tile uses a 4+4 split ({4t..4t+3} U {64+4t..+3}): fragment ds_read
// addresses stride 16B across 16 lanes -> 2-way bank alias (free) instead of
// the 4-way alias of the 8-contiguous layout (8.4e7 conflicts/dispatch in r9).
// ---------------------------------------------------------------------------
__global__ __launch_bounds__(256)
void gemm_syn(const float* __restrict__ H, float* __restrict__ C, int Nn, int K)
{
    constexpr int KS = 16;
    constexpr int LDT = 132;
    __shared__ float As[KS * LDT];
    __shared__ float Bs[KS * LDT];

    // triangular decode: blockIdx.x -> (ct, rt) with rt <= ct
    {
    }
    const int q = blockIdx.x;
    int ct = (int)((sqrtf(8.0f * (float)q + 1.0f) - 1.0f) * 0.5f);
    while ((ct + 1) * (ct + 2) / 2 <= q) ++ct;
    while (ct * (ct + 1) / 2 > q) --ct;
    const int rt = q - ct * (ct + 1) / 2;
    const int row0 = rt * 128;
    const int col0 = ct * 128;

    const int t    = threadIdx.x;
    const int tm   = t & 15;
    const int tn   = t >> 4;
    const int lrow = t >> 2;
    const int lk   = (t & 3) << 2;

    const float* Ap0 = H + (size_t)(row0 + lrow)      * K + lk;
    const float* Ap1 = H + (size_t)(row0 + lrow + 64) * K + lk;
    const float* Bp0 = H + (size_t)(col0 + lrow)      * K + lk;
    const float* Bp1 = H + (size_t)(col0 + lrow + 64) * K + lk;

    float4 a0 = *(const float4*)(Ap0);
    float4 a1 = *(const float4*)(Ap1);
    float4 b0 = *(const float4*)(Bp0);
    float4 b1 = *(const float4*)(Bp1);

    float acc[8][8];
#pragma unroll
    for (int i = 0; i < 8; ++i)
#pragma unroll
        for (int j = 0; j < 8; ++j) acc[i][j] = 0.f;

    for (int k0 = 0; k0 < K; k0 += KS) {
        __syncthreads();
        As[(lk + 0) * LDT + lrow] = a0.x;
        As[(lk + 1) * LDT + lrow] = a0.y;
        As[(lk + 2) * LDT + lrow] = a0.z;
        As[(lk + 3) * LDT + lrow] = a0.w;
        As[(lk + 0) * LDT + lrow + 64] = a1.x;
        As[(lk + 1) * LDT + lrow + 64] = a1.y;
        As[(lk + 2) * LDT + lrow + 64] = a1.z;
        As[(lk + 3) * LDT + lrow + 64] = a1.w;
        Bs[(lk + 0) * LDT + lrow] = b0.x;
        Bs[(lk + 1) * LDT + lrow] = b0.y;
        Bs[(lk + 2) * LDT + lrow] = b0.z;
        Bs[(lk + 3) * LDT + lrow] = b0.w;
        Bs[(lk + 0) * LDT + lrow + 64] = b1.x;
        Bs[(lk + 1) * LDT + lrow + 64] = b1.y;
        Bs[(lk + 2) * LDT + lrow + 64] = b1.z;
        Bs[(lk + 3) * LDT + lrow + 64] = b1.w;
        __syncthreads();
        if (k0 + KS < K) {
            a0 = *(const float4*)(Ap0 + k0 + KS);
            a1 = *(const float4*)(Ap1 + k0 + KS);
            b0 = *(const float4*)(Bp0 + k0 + KS);
            b1 = *(const float4*)(Bp1 + k0 + KS);
        }
#pragma unroll
        for (int kk = 0; kk < KS; ++kk) {
            const float4 av0 = *(const float4*)&As[kk * LDT + 4 * tm];
            const float4 av1 = *(const float4*)&As[kk * LDT + 4 * tm + 64];
            const float4 bv0 = *(const float4*)&Bs[kk * LDT + 4 * tn];
            const float4 bv1 = *(const float4*)&Bs[kk * LDT + 4 * tn + 64];
            const float a[8] = {av0.x, av0.y, av0.z, av0.w, av1.x, av1.y, av1.z, av1.w};
            const float bb[8] = {bv0.x, bv0.y, bv0.z, bv0.w, bv1.x, bv1.y, bv1.z, bv1.w};
#pragma unroll
            for (int i = 0; i < 8; ++i)
#pragma unroll
                for (int j = 0; j < 8; ++j)
                    acc[i][j] += a[i] * bb[j];
        }
    }

    // direct tile: rows {row0 + ih*64 + 4tm + i2}, cols {col0 + jh*64 + 4tn}
#pragma unroll
    for (int ih = 0; ih < 2; ++ih)
#pragma unroll
    for (int i2 = 0; i2 < 4; ++i2) {
        const int r = row0 + ih * 64 + 4 * tm + i2;
        float* Crow = C + (size_t)r * Nn + col0;
        const int ia = ih * 4 + i2;
        float4 o0 = {acc[ia][0], acc[ia][1], acc[ia][2], acc[ia][3]};
        float4 o1 = {acc[ia][4], acc[ia][5], acc[ia][6], acc[ia][7]};
        *(float4*)(Crow + 4 * tn)      = o0;
        *(float4*)(Crow + 64 + 4 * tn) = o1;
    }

    if (ct != rt) {
        // mirror tile: row = orig col, col = orig row. acc[ih*4+0..3][jj] are
        // 4 consecutive output columns -> coalesced float4 stores.
#pragma unroll
        for (int jh = 0; jh < 2; ++jh)
#pragma unroll
        for (int j2 = 0; j2 < 4; ++j2) {
            const int r = col0 + jh * 64 + 4 * tn + j2;
            float* Crow = C + (size_t)r * Nn + row0;
            const int ja = jh * 4 + j2;
            float4 o0 = {acc[0][ja], acc[1][ja], acc[2][ja], acc[3][ja]};
            float4 o1 = {acc[4][ja], acc[5][ja], acc[6][ja], acc[7][ja]};
            *(float4*)(Crow + 4 * tm)      = o0;
            *(float4*)(Crow + 64 + 4 * tm) = o1;
        }
    }
}

// ---------------------------------------------------------------------------
// Row L2-normalize: out = in / max(||in||, 1e-12). One block (128 thr) per row.
// ---------------------------------------------------------------------------
__global__ __launch_bounds__(128)
void rownorm(const float* __restrict__ in, float* __restrict__ out)
{
    __shared__ float s[2];
    const int r = blockIdx.x, t = threadIdx.x;
    const float4 v = ((const float4*)(in + (size_t)r * 512))[t];
    float ss = v.x * v.x + v.y * v.y + v.z * v.z + v.w * v.w;
#pragma unroll
    for (int off = 32; off; off >>= 1) ss += __shfl_down(ss, off);
    if ((t & 63) == 0) s[t >> 6] = ss;
    __syncthreads();
    const float den = fmaxf(sqrtf(s[0] + s[1]), 1e-12f);
    float4 o;
    o.x = v.x / den; o.y = v.y / den; o.z = v.z / den; o.w = v.w / den;
    ((float4*)(out + (size_t)r * 512))[t] = o;
}

// ---------------------------------------------------------------------------
// In-place per-row top-31 + relu via RADIX SELECT (jax.lax.top_k semantics:
// ties -> lowest index). One block (256 thr) per row. Double-buffered
// sh_pref/sh_targ; per-wave histograms; wave-0 suffix-scan (see r7 notes).
// ---------------------------------------------------------------------------
__device__ __forceinline__ unsigned mono(float f)
{
    unsigned b = __float_as_uint(f);
    return (b & 0x80000000u) ? ~b : (b | 0x80000000u);
}
__device__ __forceinline__ float unmono(unsigned u)
{
    return __uint_as_float((u & 0x80000000u) ? (u ^ 0x80000000u) : ~u);
}

__global__ __launch_bounds__(256)
void topk_radix(float* __restrict__ sim)
{
    constexpr int NC = 8192;
    __shared__ unsigned keys[NC];
    __shared__ unsigned bins4[4][256];
    __shared__ unsigned sh_pref[2], sh_targ[2];
    __shared__ int tie_idx[256];
    __shared__ int tie_cnt, sh_tie_thr;

    const int t = threadIdx.x;
    const int lane = t & 63;
    const int wid = t >> 6;
    float* row = sim + (size_t)blockIdx.x * NC;

    if (t == 0) { sh_pref[0] = 0u; sh_targ[0] = 31u; tie_cnt = 0; }
#pragma unroll
    for (int j = 0; j < 8; ++j) {
        const int i0 = 4 * (t + 256 * j);
        const float4 v = *(const float4*)&row[i0];
        uint4 k;
        k.x = mono(v.x); k.y = mono(v.y); k.z = mono(v.z); k.w = mono(v.w);
        *(uint4*)&keys[i0] = k;
    }
    __syncthreads();

    unsigned prefmask = 0u;
    for (int p = 0; p < 4; ++p) {
        const int shift = 24 - 8 * p;
#pragma unroll
        for (int w = 0; w < 4; ++w) bins4[w][t] = 0u;
        __syncthreads();
        const unsigned prefix = sh_pref[p & 1];
        const unsigned target = sh_targ[p & 1];
        for (int j = 0; j < 32; ++j) {
            const unsigned u = keys[t + 256 * j];
            if ((u & prefmask) == prefix)
                atomicAdd(&bins4[wid][(u >> shift) & 255u], 1u);
        }
        __syncthreads();
        if (wid == 0) {
            unsigned bb[4];
#pragma unroll
            for (int jj = 0; jj < 4; ++jj)
                bb[jj] = bins4[0][4 * lane + jj] + bins4[1][4 * lane + jj]
                       + bins4[2][4 * lane + jj] + bins4[3][4 * lane + jj];
            const unsigned tot = bb[0] + bb[1] + bb[2] + bb[3];
            unsigned s = tot;
#pragma unroll
            for (int off = 1; off < 64; off <<= 1) {
                const unsigned o = __shfl_down(s, off);
                if (lane + off < 64) s += o;
            }
            unsigned cge[5];
            cge[4] = s - tot;
            cge[3] = cge[4] + bb[3];
            cge[2] = cge[3] + bb[2];
            cge[1] = cge[2] + bb[1];
            cge[0] = cge[1] + bb[0];
#pragma unroll
            for (int jj = 0; jj < 4; ++jj) {
                if (cge[jj] >= target && cge[jj + 1] < target) {
                    sh_pref[(p + 1) & 1] = prefix | ((unsigned)(4 * lane + jj) << shift);
                    sh_targ[(p + 1) & 1] = target - cge[jj + 1];
                }
            }
        }
        prefmask |= (255u << shift);
        __syncthreads();
    }
    const unsigned uc = sh_pref[0];
    const int m = (int)sh_targ[0];

    for (int j = 0; j < 32; ++j) {
        const int i = t + 256 * j;
        if (keys[i] == uc) {
            const int p = atomicAdd(&tie_cnt, 1);
            if (p < 256) tie_idx[p] = i;
        }
    }
    __syncthreads();
    if (t == 0) {
        int n = tie_cnt < 256 ? tie_cnt : 256;
        for (int a = 1; a < n; ++a) {
            const int key = tie_idx[a];
            int c = a - 1;
            while (c >= 0 && tie_idx[c] > key) { tie_idx[c + 1] = tie_idx[c]; --c; }
            tie_idx[c + 1] = key;
        }
        const int mm = (m <= n ? m : n);
        sh_tie_thr = tie_idx[mm - 1];
    }
    __syncthreads();
    const int tie_thr = sh_tie_thr;

#pragma unroll
    for (int j = 0; j < 8; ++j) {
        const int i0 = 4 * (t + 256 * j);
        const uint4 k = *(const uint4*)&keys[i0];
        float4 v;
        v.x = (k.x > uc || (k.x == uc && i0 + 0 <= tie_thr)) ? fmaxf(unmono(k.x), 0.f) : 0.f;
        v.y = (k.y > uc || (k.y == uc && i0 + 1 <= tie_thr)) ? fmaxf(unmono(k.y), 0.f) : 0.f;
        v.z = (k.z > uc || (k.z == uc && i0 + 2 <= tie_thr)) ? fmaxf(unmono(k.z), 0.f) : 0.f;
        v.w = (k.w > uc || (k.w == uc && i0 + 3 <= tie_thr)) ? fmaxf(unmono(k.w), 0.f) : 0.f;
        *(float4*)&row[i0] = v;
    }
}

// ---------------------------------------------------------------------------
extern "C" void kernel_launch(void* const* d_in, const int* in_sizes, int n_in,
                              void* d_out, int out_size, void* d_ws, size_t ws_size,
                              hipStream_t stream)
{
    const float* x = (const float*)d_in[0];
    const float* W = (const float*)d_in[1];
    const float* b = (const float*)d_in[2];
    float* out = (float*)d_out;               // f32 [8192, 8192] = 268 MB

    const int N = 8192, D = 512;

    // MLP scratch lives in d_out: these bytes are dead before the sim GEMM
    // overwrites the full output (sim GEMM reads only hn, which is in ws).
    float* h1 = out;                          // f32, bytes [0, 16.8MB)
    float* h2 = out + (size_t)N * D;          // f32, bytes [16.8, 33.6MB)
    float* hn = (float*)d_ws;                 // f32, 16.8MB — only ws use

    dim3 tb(256);
    // MLP layer 0 (+relu) and layer 1
    gemm_nt<<<dim3(D / 128, N / 128), tb, 0, stream>>>(x,  W,                 b,     h1, N, D, D, 1);
    gemm_nt<<<dim3(D / 128, N / 128), tb, 0, stream>>>(h1, W + (size_t)D * D, b + D, h2, N, D, D, 0);
    // L2 normalize rows: h2 (d_out scratch) -> hn (ws)
    rownorm<<<N, 128, 0, stream>>>(h2, hn);
    // sim = hn @ hn^T, symmetric: triangular tile grid, mirror writes
    const int T = N / 128;                    // 64 tiles/side
    gemm_syn<<<T * (T + 1) / 2, tb, 0, stream>>>(hn, out, N, D);
    // per-row top-31 + relu, in place (radix select)
    topk_radix<<<N, tb, 0, stream>>>(out);
}

// Round 11
// 929.590 us; speedup vs baseline: 2.1100x; 1.3266x over previous
//
#include <hip/hip_runtime.h>
#include <hip/hip_bf16.h>

typedef __attribute__((ext_vector_type(8))) short bf16x8;
typedef __attribute__((ext_vector_type(8))) unsigned short u16x8;
typedef __attribute__((ext_vector_type(4))) float f32x4;

// ---------------------------------------------------------------------------
// f32 GEMM, "NT": C[M,N] = A[M,K]*B[N,K]^T (+bias)(relu). MLP layers only.
// ---------------------------------------------------------------------------
__global__ __launch_bounds__(256)
void gemm_nt(const float* __restrict__ A, const float* __restrict__ B,
             const float* __restrict__ bias, float* __restrict__ C,
             int M, int N, int K, int do_relu)
{
    constexpr int KS = 16;
    constexpr int LDT = 132;
    __shared__ float As[KS * LDT];
    __shared__ float Bs[KS * LDT];

    const int t    = threadIdx.x;
    const int row0 = blockIdx.y * 128;
    const int col0 = blockIdx.x * 128;
    const int tm   = t & 15;
    const int tn   = t >> 4;
    const int lrow = t >> 2;
    const int lk   = (t & 3) << 2;

    const float* Ap0 = A + (size_t)(row0 + lrow)      * K + lk;
    const float* Ap1 = A + (size_t)(row0 + lrow + 64) * K + lk;
    const float* Bp0 = B + (size_t)(col0 + lrow)      * K + lk;
    const float* Bp1 = B + (size_t)(col0 + lrow + 64) * K + lk;

    float4 a0 = *(const float4*)(Ap0);
    float4 a1 = *(const float4*)(Ap1);
    float4 b0 = *(const float4*)(Bp0);
    float4 b1 = *(const float4*)(Bp1);

    float acc[8][8];
#pragma unroll
    for (int i = 0; i < 8; ++i)
#pragma unroll
        for (int j = 0; j < 8; ++j) acc[i][j] = 0.f;

    for (int k0 = 0; k0 < K; k0 += KS) {
        __syncthreads();
        As[(lk + 0) * LDT + lrow] = a0.x;
        As[(lk + 1) * LDT + lrow] = a0.y;
        As[(lk + 2) * LDT + lrow] = a0.z;
        As[(lk + 3) * LDT + lrow] = a0.w;
        As[(lk + 0) * LDT + lrow + 64] = a1.x;
        As[(lk + 1) * LDT + lrow + 64] = a1.y;
        As[(lk + 2) * LDT + lrow + 64] = a1.z;
        As[(lk + 3) * LDT + lrow + 64] = a1.w;
        Bs[(lk + 0) * LDT + lrow] = b0.x;
        Bs[(lk + 1) * LDT + lrow] = b0.y;
        Bs[(lk + 2) * LDT + lrow] = b0.z;
        Bs[(lk + 3) * LDT + lrow] = b0.w;
        Bs[(lk + 0) * LDT + lrow + 64] = b1.x;
        Bs[(lk + 1) * LDT + lrow + 64] = b1.y;
        Bs[(lk + 2) * LDT + lrow + 64] = b1.z;
        Bs[(lk + 3) * LDT + lrow + 64] = b1.w;
        __syncthreads();
        if (k0 + KS < K) {
            a0 = *(const float4*)(Ap0 + k0 + KS);
            a1 = *(const float4*)(Ap1 + k0 + KS);
            b0 = *(const float4*)(Bp0 + k0 + KS);
            b1 = *(const float4*)(Bp1 + k0 + KS);
        }
#pragma unroll
        for (int kk = 0; kk < KS; ++kk) {
            const float4 av0 = *(const float4*)&As[kk * LDT + 8 * tm];
            const float4 av1 = *(const float4*)&As[kk * LDT + 8 * tm + 4];
            const float4 bv0 = *(const float4*)&Bs[kk * LDT + 8 * tn];
            const float4 bv1 = *(const float4*)&Bs[kk * LDT + 8 * tn + 4];
            const float a[8] = {av0.x, av0.y, av0.z, av0.w, av1.x, av1.y, av1.z, av1.w};
            const float bb[8] = {bv0.x, bv0.y, bv0.z, bv0.w, bv1.x, bv1.y, bv1.z, bv1.w};
#pragma unroll
            for (int i = 0; i < 8; ++i)
#pragma unroll
                for (int j = 0; j < 8; ++j)
                    acc[i][j] += a[i] * bb[j];
        }
    }

#pragma unroll
    for (int i = 0; i < 8; ++i) {
        const int r = row0 + 8 * tm + i;
        float* Crow = C + (size_t)r * N + col0 + 8 * tn;
        float o[8];
#pragma unroll
        for (int j = 0; j < 8; ++j) o[j] = acc[i][j];
        if (bias) {
#pragma unroll
            for (int j = 0; j < 8; ++j) o[j] += bias[col0 + 8 * tn + j];
        }
        if (do_relu) {
#pragma unroll
            for (int j = 0; j < 8; ++j) o[j] = fmaxf(o[j], 0.f);
        }
        float4 o0 = {o[0], o[1], o[2], o[3]};
        float4 o1 = {o[4], o[5], o[6], o[7]};
        *(float4*)(Crow)     = o0;
        *(float4*)(Crow + 4) = o1;
    }
}

// ---------------------------------------------------------------------------
// Row L2-normalize + bf16x3 SPLIT: v = x/max(||x||,1e-12); hi=bf16(v),
// mid=bf16(v-hi), lo=bf16(v-hi-mid). Exact f32 value ~= hi+mid+lo (resid
// <= 2^-27 rel). One block (128 thr) per row, 4 elems/thread.
// ---------------------------------------------------------------------------
__global__ __launch_bounds__(128)
void rownorm_split(const float* __restrict__ in, unsigned short* __restrict__ Hhi,
                   unsigned short* __restrict__ Hmid, unsigned short* __restrict__ Hlo)
{
    __shared__ float s[2];
    const int r = blockIdx.x, t = threadIdx.x;
    const float4 v = ((const float4*)(in + (size_t)r * 512))[t];
    float ss = v.x * v.x + v.y * v.y + v.z * v.z + v.w * v.w;
#pragma unroll
    for (int off = 32; off; off >>= 1) ss += __shfl_down(ss, off);
    if ((t & 63) == 0) s[t >> 6] = ss;
    __syncthreads();
    const float den = fmaxf(sqrtf(s[0] + s[1]), 1e-12f);
    const float f[4] = {v.x / den, v.y / den, v.z / den, v.w / den};
    ushort4 uh, um, ul;
    unsigned short* ph = (unsigned short*)&uh;
    unsigned short* pm = (unsigned short*)&um;
    unsigned short* pl = (unsigned short*)&ul;
#pragma unroll
    for (int j = 0; j < 4; ++j) {
        const __hip_bfloat16 h = __float2bfloat16(f[j]);
        const float fh = __bfloat162float(h);
        const float r1 = f[j] - fh;
        const __hip_bfloat16 m = __float2bfloat16(r1);
        const float fm = __bfloat162float(m);
        const float r2 = r1 - fm;
        const __hip_bfloat16 l = __float2bfloat16(r2);
        ph[j] = *(const unsigned short*)&h;
        pm[j] = *(const unsigned short*)&m;
        pl[j] = *(const unsigned short*)&l;
    }
    const size_t o = (size_t)r * 512 + 4 * t;
    *(ushort4*)(Hhi  + o) = uh;
    *(ushort4*)(Hmid + o) = um;
    *(ushort4*)(Hlo  + o) = ul;
}

// ---------------------------------------------------------------------------
// SYMMETRIC sim GEMM via bf16x3 MFMA: C = H*H^T with H ~= hi+mid+lo.
// 6 products (hh, hm, mh, mm, hl, lh) accumulate into ONE f32 acc; dropped
// terms <= 2^-27 (below f32 reorder noise). Triangular tile grid (2080
// blocks, 128x128 tile). 4 waves, each owns a 64x64 sub-tile = 4x4 frags of
// v_mfma_f32_16x16x32_bf16. LDS: 6 tiles [128 rows][32 bf16] at 80B row
// stride (16B-aligned b128 ops, 2-way bank alias = free). Fragment map:
// A/B lane l holds row/col (l&15), k=8*(l>>4)..+7; C/D col=lane&15,
// row=(lane>>4)*4+reg [m89-verified]. Mirror tiles written transposed
// (scalar stores; tile-local so L2 write-combines).
// ---------------------------------------------------------------------------
__global__ __launch_bounds__(256)
void gemm_sym_mfma(const unsigned short* __restrict__ Hhi,
                   const unsigned short* __restrict__ Hmid,
                   const unsigned short* __restrict__ Hlo,
                   float* __restrict__ C, int Nn)
{
    constexpr int K  = 512;
    constexpr int KC = 32;   // k-chunk (bf16 elems)
    constexpr int LR = 40;   // LDS row stride in bf16 (80B: aligned + 2-way)
    __shared__ unsigned short lds[6 * 128 * LR];   // 61.4 KB

    const int q = blockIdx.x;
    int ct = (int)((sqrtf(8.0f * (float)q + 1.0f) - 1.0f) * 0.5f);
    while ((ct + 1) * (ct + 2) / 2 <= q) ++ct;
    while (ct * (ct + 1) / 2 > q) --ct;
    const int rt = q - ct * (ct + 1) / 2;
    const int row0 = rt * 128;
    const int col0 = ct * 128;

    const int t    = threadIdx.x;
    const int lane = t & 63;
    const int wid  = t >> 6;
    const int wr   = (wid >> 1) * 64;   // wave row base in tile
    const int wc   = (wid & 1) * 64;    // wave col base in tile

    // staging map: thread t loads row r=t>>1, k-half kh=t&1 (16 bf16) per array
    const int r  = t >> 1;
    const int kh = (t & 1) * 16;
    const unsigned short* srcs[6] = {
        Hhi  + (size_t)(row0 + r) * K, Hmid + (size_t)(row0 + r) * K, Hlo + (size_t)(row0 + r) * K,
        Hhi  + (size_t)(col0 + r) * K, Hmid + (size_t)(col0 + r) * K, Hlo + (size_t)(col0 + r) * K };

    u16x8 pf[12];
#pragma unroll
    for (int a = 0; a < 6; ++a) {
        pf[2 * a]     = *(const u16x8*)(srcs[a] + kh);
        pf[2 * a + 1] = *(const u16x8*)(srcs[a] + kh + 8);
    }

    f32x4 acc[4][4];
#pragma unroll
    for (int i = 0; i < 4; ++i)
#pragma unroll
        for (int j = 0; j < 4; ++j) acc[i][j] = (f32x4){0.f, 0.f, 0.f, 0.f};

    const int fro = (lane & 15) * LR + 8 * (lane >> 4);   // frag row/col base offset

    for (int k0 = 0; k0 < K; k0 += KC) {
        __syncthreads();
#pragma unroll
        for (int a = 0; a < 6; ++a) {
            *(u16x8*)&lds[a * 128 * LR + r * LR + kh]     = pf[2 * a];
            *(u16x8*)&lds[a * 128 * LR + r * LR + kh + 8] = pf[2 * a + 1];
        }
        __syncthreads();
        if (k0 + KC < K) {
#pragma unroll
            for (int a = 0; a < 6; ++a) {
                pf[2 * a]     = *(const u16x8*)(srcs[a] + k0 + KC + kh);
                pf[2 * a + 1] = *(const u16x8*)(srcs[a] + k0 + KC + kh + 8);
            }
        }
        bf16x8 af[3][4], bf[3][4];
#pragma unroll
        for (int p = 0; p < 3; ++p)
#pragma unroll
            for (int ti = 0; ti < 4; ++ti) {
                af[p][ti] = *(const bf16x8*)&lds[p * 128 * LR + (wr + ti * 16) * LR + fro];
                bf[p][ti] = *(const bf16x8*)&lds[(3 + p) * 128 * LR + (wc + ti * 16) * LR + fro];
            }
#pragma unroll
        for (int ti = 0; ti < 4; ++ti)
#pragma unroll
            for (int tj = 0; tj < 4; ++tj) {
                f32x4 c = acc[ti][tj];
                c = __builtin_amdgcn_mfma_f32_16x16x32_bf16(af[0][ti], bf[0][tj], c, 0, 0, 0);
                c = __builtin_amdgcn_mfma_f32_16x16x32_bf16(af[0][ti], bf[1][tj], c, 0, 0, 0);
                c = __builtin_amdgcn_mfma_f32_16x16x32_bf16(af[1][ti], bf[0][tj], c, 0, 0, 0);
                c = __builtin_amdgcn_mfma_f32_16x16x32_bf16(af[1][ti], bf[1][tj], c, 0, 0, 0);
                c = __builtin_amdgcn_mfma_f32_16x16x32_bf16(af[0][ti], bf[2][tj], c, 0, 0, 0);
                c = __builtin_amdgcn_mfma_f32_16x16x32_bf16(af[2][ti], bf[0][tj], c, 0, 0, 0);
                acc[ti][tj] = c;
            }
    }

    const int crow = (lane >> 4) * 4;   // C/D: row=(lane>>4)*4+reg, col=lane&15
    const int ccol = lane & 15;
#pragma unroll
    for (int ti = 0; ti < 4; ++ti)
#pragma unroll
        for (int tj = 0; tj < 4; ++tj)
#pragma unroll
            for (int qq = 0; qq < 4; ++qq) {
                const int rr = row0 + wr + ti * 16 + crow + qq;
                const int cc = col0 + wc + tj * 16 + ccol;
                C[(size_t)rr * Nn + cc] = acc[ti][tj][qq];
            }
    if (ct != rt) {
#pragma unroll
        for (int ti = 0; ti < 4; ++ti)
#pragma unroll
            for (int tj = 0; tj < 4; ++tj)
#pragma unroll
                for (int qq = 0; qq < 4; ++qq) {
                    const int rr = row0 + wr + ti * 16 + crow + qq;
                    const int cc = col0 + wc + tj * 16 + ccol;
                    C[(size_t)cc * Nn + rr] = acc[ti][tj][qq];
                }
    }
}

// ---------------------------------------------------------------------------
// Fallback f32 path (r10, proven): rownorm + symmetric f32 GEMM.
// ---------------------------------------------------------------------------
__global__ __launch_bounds__(128)
void rownorm(const float* __restrict__ in, float* __restrict__ out)
{
    __shared__ float s[2];
    const int r = blockIdx.x, t = threadIdx.x;
    const float4 v = ((const float4*)(in + (size_t)r * 512))[t];
    float ss = v.x * v.x + v.y * v.y + v.z * v.z + v.w * v.w;
#pragma unroll
    for (int off = 32; off; off >>= 1) ss += __shfl_down(ss, off);
    if ((t & 63) == 0) s[t >> 6] = ss;
    __syncthreads();
    const float den = fmaxf(sqrtf(s[0] + s[1]), 1e-12f);
    float4 o;
    o.x = v.x / den; o.y = v.y / den; o.z = v.z / den; o.w = v.w / den;
    ((float4*)(out + (size_t)r * 512))[t] = o;
}

__global__ __launch_bounds__(256)
void gemm_syn(const float* __restrict__ H, float* __restrict__ C, int Nn, int K)
{
    constexpr int KS = 16;
    constexpr int LDT = 132;
    __shared__ float As[KS * LDT];
    __shared__ float Bs[KS * LDT];

    const int q = blockIdx.x;
    int ct = (int)((sqrtf(8.0f * (float)q + 1.0f) - 1.0f) * 0.5f);
    while ((ct + 1) * (ct + 2) / 2 <= q) ++ct;
    while (ct * (ct + 1) / 2 > q) --ct;
    const int rt = q - ct * (ct + 1) / 2;
    const int row0 = rt * 128;
    const int col0 = ct * 128;

    const int t    = threadIdx.x;
    const int tm   = t & 15;
    const int tn   = t >> 4;
    const int lrow = t >> 2;
    const int lk   = (t & 3) << 2;

    const float* Ap0 = H + (size_t)(row0 + lrow)      * K + lk;
    const float* Ap1 = H + (size_t)(row0 + lrow + 64) * K + lk;
    const float* Bp0 = H + (size_t)(col0 + lrow)      * K + lk;
    const float* Bp1 = H + (size_t)(col0 + lrow + 64) * K + lk;

    float4 a0 = *(const float4*)(Ap0);
    float4 a1 = *(const float4*)(Ap1);
    float4 b0 = *(const float4*)(Bp0);
    float4 b1 = *(const float4*)(Bp1);

    float acc[8][8];
#pragma unroll
    for (int i = 0; i < 8; ++i)
#pragma unroll
        for (int j = 0; j < 8; ++j) acc[i][j] = 0.f;

    for (int k0 = 0; k0 < K; k0 += KS) {
        __syncthreads();
        As[(lk + 0) * LDT + lrow] = a0.x;
        As[(lk + 1) * LDT + lrow] = a0.y;
        As[(lk + 2) * LDT + lrow] = a0.z;
        As[(lk + 3) * LDT + lrow] = a0.w;
        As[(lk + 0) * LDT + lrow + 64] = a1.x;
        As[(lk + 1) * LDT + lrow + 64] = a1.y;
        As[(lk + 2) * LDT + lrow + 64] = a1.z;
        As[(lk + 3) * LDT + lrow + 64] = a1.w;
        Bs[(lk + 0) * LDT + lrow] = b0.x;
        Bs[(lk + 1) * LDT + lrow] = b0.y;
        Bs[(lk + 2) * LDT + lrow] = b0.z;
        Bs[(lk + 3) * LDT + lrow] = b0.w;
        Bs[(lk + 0) * LDT + lrow + 64] = b1.x;
        Bs[(lk + 1) * LDT + lrow + 64] = b1.y;
        Bs[(lk + 2) * LDT + lrow + 64] = b1.z;
        Bs[(lk + 3) * LDT + lrow + 64] = b1.w;
        __syncthreads();
        if (k0 + KS < K) {
            a0 = *(const float4*)(Ap0 + k0 + KS);
            a1 = *(const float4*)(Ap1 + k0 + KS);
            b0 = *(const float4*)(Bp0 + k0 + KS);
            b1 = *(const float4*)(Bp1 + k0 + KS);
        }
#pragma unroll
        for (int kk = 0; kk < KS; ++kk) {
            const float4 av0 = *(const float4*)&As[kk * LDT + 4 * tm];
            const float4 av1 = *(const float4*)&As[kk * LDT + 4 * tm + 64];
            const float4 bv0 = *(const float4*)&Bs[kk * LDT + 4 * tn];
            const float4 bv1 = *(const float4*)&Bs[kk * LDT + 4 * tn + 64];
            const float a[8] = {av0.x, av0.y, av0.z, av0.w, av1.x, av1.y, av1.z, av1.w};
            const float bb[8] = {bv0.x, bv0.y, bv0.z, bv0.w, bv1.x, bv1.y, bv1.z, bv1.w};
#pragma unroll
            for (int i = 0; i < 8; ++i)
#pragma unroll
                for (int j = 0; j < 8; ++j)
                    acc[i][j] += a[i] * bb[j];
        }
    }

#pragma unroll
    for (int ih = 0; ih < 2; ++ih)
#pragma unroll
    for (int i2 = 0; i2 < 4; ++i2) {
        const int rr = row0 + ih * 64 + 4 * tm + i2;
        float* Crow = C + (size_t)rr * Nn + col0;
        const int ia = ih * 4 + i2;
        float4 o0 = {acc[ia][0], acc[ia][1], acc[ia][2], acc[ia][3]};
        float4 o1 = {acc[ia][4], acc[ia][5], acc[ia][6], acc[ia][7]};
        *(float4*)(Crow + 4 * tn)      = o0;
        *(float4*)(Crow + 64 + 4 * tn) = o1;
    }
    if (ct != rt) {
#pragma unroll
        for (int jh = 0; jh < 2; ++jh)
#pragma unroll
        for (int j2 = 0; j2 < 4; ++j2) {
            const int rr = col0 + jh * 64 + 4 * tn + j2;
            float* Crow = C + (size_t)rr * Nn + row0;
            const int ja = jh * 4 + j2;
            float4 o0 = {acc[0][ja], acc[1][ja], acc[2][ja], acc[3][ja]};
            float4 o1 = {acc[4][ja], acc[5][ja], acc[6][ja], acc[7][ja]};
            *(float4*)(Crow + 4 * tm)      = o0;
            *(float4*)(Crow + 64 + 4 * tm) = o1;
        }
    }
}

// ---------------------------------------------------------------------------
// In-place per-row top-31 + relu via RADIX SELECT (jax.lax.top_k semantics).
// ---------------------------------------------------------------------------
__device__ __forceinline__ unsigned mono(float f)
{
    unsigned b = __float_as_uint(f);
    return (b & 0x80000000u) ? ~b : (b | 0x80000000u);
}
__device__ __forceinline__ float unmono(unsigned u)
{
    return __uint_as_float((u & 0x80000000u) ? (u ^ 0x80000000u) : ~u);
}

__global__ __launch_bounds__(256)
void topk_radix(float* __restrict__ sim)
{
    constexpr int NC = 8192;
    __shared__ unsigned keys[NC];
    __shared__ unsigned bins4[4][256];
    __shared__ unsigned sh_pref[2], sh_targ[2];
    __shared__ int tie_idx[256];
    __shared__ int tie_cnt, sh_tie_thr;

    const int t = threadIdx.x;
    const int lane = t & 63;
    const int wid = t >> 6;
    float* row = sim + (size_t)blockIdx.x * NC;

    if (t == 0) { sh_pref[0] = 0u; sh_targ[0] = 31u; tie_cnt = 0; }
#pragma unroll
    for (int j = 0; j < 8; ++j) {
        const int i0 = 4 * (t + 256 * j);
        const float4 v = *(const float4*)&row[i0];
        uint4 k;
        k.x = mono(v.x); k.y = mono(v.y); k.z = mono(v.z); k.w = mono(v.w);
        *(uint4*)&keys[i0] = k;
    }
    __syncthreads();

    unsigned prefmask = 0u;
    for (int p = 0; p < 4; ++p) {
        const int shift = 24 - 8 * p;
#pragma unroll
        for (int w = 0; w < 4; ++w) bins4[w][t] = 0u;
        __syncthreads();
        const unsigned prefix = sh_pref[p & 1];
        const unsigned target = sh_targ[p & 1];
        for (int j = 0; j < 32; ++j) {
            const unsigned u = keys[t + 256 * j];
            if ((u & prefmask) == prefix)
                atomicAdd(&bins4[wid][(u >> shift) & 255u], 1u);
        }
        __syncthreads();
        if (wid == 0) {
            unsigned bb[4];
#pragma unroll
            for (int jj = 0; jj < 4; ++jj)
                bb[jj] = bins4[0][4 * lane + jj] + bins4[1][4 * lane + jj]
                       + bins4[2][4 * lane + jj] + bins4[3][4 * lane + jj];
            const unsigned tot = bb[0] + bb[1] + bb[2] + bb[3];
            unsigned s = tot;
#pragma unroll
            for (int off = 1; off < 64; off <<= 1) {
                const unsigned o = __shfl_down(s, off);
                if (lane + off < 64) s += o;
            }
            unsigned cge[5];
            cge[4] = s - tot;
            cge[3] = cge[4] + bb[3];
            cge[2] = cge[3] + bb[2];
            cge[1] = cge[2] + bb[1];
            cge[0] = cge[1] + bb[0];
#pragma unroll
            for (int jj = 0; jj < 4; ++jj) {
                if (cge[jj] >= target && cge[jj + 1] < target) {
                    sh_pref[(p + 1) & 1] = prefix | ((unsigned)(4 * lane + jj) << shift);
                    sh_targ[(p + 1) & 1] = target - cge[jj + 1];
                }
            }
        }
        prefmask |= (255u << shift);
        __syncthreads();
    }
    const unsigned uc = sh_pref[0];
    const int m = (int)sh_targ[0];

    for (int j = 0; j < 32; ++j) {
        const int i = t + 256 * j;
        if (keys[i] == uc) {
            const int p = atomicAdd(&tie_cnt, 1);
            if (p < 256) tie_idx[p] = i;
        }
    }
    __syncthreads();
    if (t == 0) {
        int n = tie_cnt < 256 ? tie_cnt : 256;
        for (int a = 1; a < n; ++a) {
            const int key = tie_idx[a];
            int c = a - 1;
            while (c >= 0 && tie_idx[c] > key) { tie_idx[c + 1] = tie_idx[c]; --c; }
            tie_idx[c + 1] = key;
        }
        const int mm = (m <= n ? m : n);
        sh_tie_thr = tie_idx[mm - 1];
    }
    __syncthreads();
    const int tie_thr = sh_tie_thr;

#pragma unroll
    for (int j = 0; j < 8; ++j) {
        const int i0 = 4 * (t + 256 * j);
        const uint4 k = *(const uint4*)&keys[i0];
        float4 v;
        v.x = (k.x > uc || (k.x == uc && i0 + 0 <= tie_thr)) ? fmaxf(unmono(k.x), 0.f) : 0.f;
        v.y = (k.y > uc || (k.y == uc && i0 + 1 <= tie_thr)) ? fmaxf(unmono(k.y), 0.f) : 0.f;
        v.z = (k.z > uc || (k.z == uc && i0 + 2 <= tie_thr)) ? fmaxf(unmono(k.z), 0.f) : 0.f;
        v.w = (k.w > uc || (k.w == uc && i0 + 3 <= tie_thr)) ? fmaxf(unmono(k.w), 0.f) : 0.f;
        *(float4*)&row[i0] = v;
    }
}

// ---------------------------------------------------------------------------
extern "C" void kernel_launch(void* const* d_in, const int* in_sizes, int n_in,
                              void* d_out, int out_size, void* d_ws, size_t ws_size,
                              hipStream_t stream)
{
    const float* x = (const float*)d_in[0];
    const float* W = (const float*)d_in[1];
    const float* b = (const float*)d_in[2];
    float* out = (float*)d_out;               // f32 [8192, 8192] = 268 MB

    const int N = 8192, D = 512;
    const int T = N / 128;

    // MLP scratch in d_out (dead before sim GEMM overwrites the full output)
    float* h1 = out;
    float* h2 = out + (size_t)N * D;

    dim3 tb(256);
    gemm_nt<<<dim3(D / 128, N / 128), tb, 0, stream>>>(x,  W,                 b,     h1, N, D, D, 1);
    gemm_nt<<<dim3(D / 128, N / 128), tb, 0, stream>>>(h1, W + (size_t)D * D, b + D, h2, N, D, D, 0);

    const size_t split_bytes = (size_t)3 * N * D * sizeof(unsigned short); // 25.2 MB
    if (ws_size >= split_bytes) {
        // bf16x3 MFMA path
        unsigned short* Hhi  = (unsigned short*)d_ws;
        unsigned short* Hmid = Hhi  + (size_t)N * D;
        unsigned short* Hlo  = Hmid + (size_t)N * D;
        rownorm_split<<<N, 128, 0, stream>>>(h2, Hhi, Hmid, Hlo);
        gemm_sym_mfma<<<T * (T + 1) / 2, tb, 0, stream>>>(Hhi, Hmid, Hlo, out, N);
    } else {
        // f32 fallback (r10-proven)
        float* hn = (float*)d_ws;
        rownorm<<<N, 128, 0, stream>>>(h2, hn);
        gemm_syn<<<T * (T + 1) / 2, tb, 0, stream>>>(hn, out, N, D);
    }
    topk_radix<<<N, tb, 0, stream>>>(out);
}

// Round 12
// 758.320 us; speedup vs baseline: 2.5866x; 1.2259x over previous
//
#include <hip/hip_runtime.h>
#include <hip/hip_bf16.h>

typedef __attribute__((ext_vector_type(8))) short bf16x8;
typedef __attribute__((ext_vector_type(8))) unsigned short u16x8;
typedef __attribute__((ext_vector_type(4))) float f32x4;

// ---------------------------------------------------------------------------
// f32 GEMM, "NT": C[M,N] = A[M,K]*B[N,K]^T (+bias)(relu). MLP layers only.
// ---------------------------------------------------------------------------
__global__ __launch_bounds__(256)
void gemm_nt(const float* __restrict__ A, const float* __restrict__ B,
             const float* __restrict__ bias, float* __restrict__ C,
             int M, int N, int K, int do_relu)
{
    constexpr int KS = 16;
    constexpr int LDT = 132;
    __shared__ float As[KS * LDT];
    __shared__ float Bs[KS * LDT];

    const int t    = threadIdx.x;
    const int row0 = blockIdx.y * 128;
    const int col0 = blockIdx.x * 128;
    const int tm   = t & 15;
    const int tn   = t >> 4;
    const int lrow = t >> 2;
    const int lk   = (t & 3) << 2;

    const float* Ap0 = A + (size_t)(row0 + lrow)      * K + lk;
    const float* Ap1 = A + (size_t)(row0 + lrow + 64) * K + lk;
    const float* Bp0 = B + (size_t)(col0 + lrow)      * K + lk;
    const float* Bp1 = B + (size_t)(col0 + lrow + 64) * K + lk;

    float4 a0 = *(const float4*)(Ap0);
    float4 a1 = *(const float4*)(Ap1);
    float4 b0 = *(const float4*)(Bp0);
    float4 b1 = *(const float4*)(Bp1);

    float acc[8][8];
#pragma unroll
    for (int i = 0; i < 8; ++i)
#pragma unroll
        for (int j = 0; j < 8; ++j) acc[i][j] = 0.f;

    for (int k0 = 0; k0 < K; k0 += KS) {
        __syncthreads();
        As[(lk + 0) * LDT + lrow] = a0.x;
        As[(lk + 1) * LDT + lrow] = a0.y;
        As[(lk + 2) * LDT + lrow] = a0.z;
        As[(lk + 3) * LDT + lrow] = a0.w;
        As[(lk + 0) * LDT + lrow + 64] = a1.x;
        As[(lk + 1) * LDT + lrow + 64] = a1.y;
        As[(lk + 2) * LDT + lrow + 64] = a1.z;
        As[(lk + 3) * LDT + lrow + 64] = a1.w;
        Bs[(lk + 0) * LDT + lrow] = b0.x;
        Bs[(lk + 1) * LDT + lrow] = b0.y;
        Bs[(lk + 2) * LDT + lrow] = b0.z;
        Bs[(lk + 3) * LDT + lrow] = b0.w;
        Bs[(lk + 0) * LDT + lrow + 64] = b1.x;
        Bs[(lk + 1) * LDT + lrow + 64] = b1.y;
        Bs[(lk + 2) * LDT + lrow + 64] = b1.z;
        Bs[(lk + 3) * LDT + lrow + 64] = b1.w;
        __syncthreads();
        if (k0 + KS < K) {
            a0 = *(const float4*)(Ap0 + k0 + KS);
            a1 = *(const float4*)(Ap1 + k0 + KS);
            b0 = *(const float4*)(Bp0 + k0 + KS);
            b1 = *(const float4*)(Bp1 + k0 + KS);
        }
#pragma unroll
        for (int kk = 0; kk < KS; ++kk) {
            const float4 av0 = *(const float4*)&As[kk * LDT + 8 * tm];
            const float4 av1 = *(const float4*)&As[kk * LDT + 8 * tm + 4];
            const float4 bv0 = *(const float4*)&Bs[kk * LDT + 8 * tn];
            const float4 bv1 = *(const float4*)&Bs[kk * LDT + 8 * tn + 4];
            const float a[8] = {av0.x, av0.y, av0.z, av0.w, av1.x, av1.y, av1.z, av1.w};
            const float bb[8] = {bv0.x, bv0.y, bv0.z, bv0.w, bv1.x, bv1.y, bv1.z, bv1.w};
#pragma unroll
            for (int i = 0; i < 8; ++i)
#pragma unroll
                for (int j = 0; j < 8; ++j)
                    acc[i][j] += a[i] * bb[j];
        }
    }

#pragma unroll
    for (int i = 0; i < 8; ++i) {
        const int r = row0 + 8 * tm + i;
        float* Crow = C + (size_t)r * N + col0 + 8 * tn;
        float o[8];
#pragma unroll
        for (int j = 0; j < 8; ++j) o[j] = acc[i][j];
        if (bias) {
#pragma unroll
            for (int j = 0; j < 8; ++j) o[j] += bias[col0 + 8 * tn + j];
        }
        if (do_relu) {
#pragma unroll
            for (int j = 0; j < 8; ++j) o[j] = fmaxf(o[j], 0.f);
        }
        float4 o0 = {o[0], o[1], o[2], o[3]};
        float4 o1 = {o[4], o[5], o[6], o[7]};
        *(float4*)(Crow)     = o0;
        *(float4*)(Crow + 4) = o1;
    }
}

// ---------------------------------------------------------------------------
// Row L2-normalize + bf16x3 SPLIT (hi/mid/lo; resid <= 2^-27 rel).
// ---------------------------------------------------------------------------
__global__ __launch_bounds__(128)
void rownorm_split(const float* __restrict__ in, unsigned short* __restrict__ Hhi,
                   unsigned short* __restrict__ Hmid, unsigned short* __restrict__ Hlo)
{
    __shared__ float s[2];
    const int r = blockIdx.x, t = threadIdx.x;
    const float4 v = ((const float4*)(in + (size_t)r * 512))[t];
    float ss = v.x * v.x + v.y * v.y + v.z * v.z + v.w * v.w;
#pragma unroll
    for (int off = 32; off; off >>= 1) ss += __shfl_down(ss, off);
    if ((t & 63) == 0) s[t >> 6] = ss;
    __syncthreads();
    const float den = fmaxf(sqrtf(s[0] + s[1]), 1e-12f);
    const float f[4] = {v.x / den, v.y / den, v.z / den, v.w / den};
    ushort4 uh, um, ul;
    unsigned short* ph = (unsigned short*)&uh;
    unsigned short* pm = (unsigned short*)&um;
    unsigned short* pl = (unsigned short*)&ul;
#pragma unroll
    for (int j = 0; j < 4; ++j) {
        const __hip_bfloat16 h = __float2bfloat16(f[j]);
        const float fh = __bfloat162float(h);
        const float r1 = f[j] - fh;
        const __hip_bfloat16 m = __float2bfloat16(r1);
        const float fm = __bfloat162float(m);
        const float r2 = r1 - fm;
        const __hip_bfloat16 l = __float2bfloat16(r2);
        ph[j] = *(const unsigned short*)&h;
        pm[j] = *(const unsigned short*)&m;
        pl[j] = *(const unsigned short*)&l;
    }
    const size_t o = (size_t)r * 512 + 4 * t;
    *(ushort4*)(Hhi  + o) = uh;
    *(ushort4*)(Hmid + o) = um;
    *(ushort4*)(Hlo  + o) = ul;
}

// ---------------------------------------------------------------------------
// SYMMETRIC sim GEMM via bf16x3 MFMA (r11-proven). Triangular grid, 128x128
// tile, 4 waves x 4x4 frags of v_mfma_f32_16x16x32_bf16, 6 split-products.
// ---------------------------------------------------------------------------
__global__ __launch_bounds__(256)
void gemm_sym_mfma(const unsigned short* __restrict__ Hhi,
                   const unsigned short* __restrict__ Hmid,
                   const unsigned short* __restrict__ Hlo,
                   float* __restrict__ C, int Nn)
{
    constexpr int K  = 512;
    constexpr int KC = 32;
    constexpr int LR = 40;
    __shared__ unsigned short lds[6 * 128 * LR];

    const int q = blockIdx.x;
    int ct = (int)((sqrtf(8.0f * (float)q + 1.0f) - 1.0f) * 0.5f);
    while ((ct + 1) * (ct + 2) / 2 <= q) ++ct;
    while (ct * (ct + 1) / 2 > q) --ct;
    const int rt = q - ct * (ct + 1) / 2;
    const int row0 = rt * 128;
    const int col0 = ct * 128;

    const int t    = threadIdx.x;
    const int lane = t & 63;
    const int wid  = t >> 6;
    const int wr   = (wid >> 1) * 64;
    const int wc   = (wid & 1) * 64;

    const int r  = t >> 1;
    const int kh = (t & 1) * 16;
    const unsigned short* srcs[6] = {
        Hhi  + (size_t)(row0 + r) * K, Hmid + (size_t)(row0 + r) * K, Hlo + (size_t)(row0 + r) * K,
        Hhi  + (size_t)(col0 + r) * K, Hmid + (size_t)(col0 + r) * K, Hlo + (size_t)(col0 + r) * K };

    u16x8 pf[12];
#pragma unroll
    for (int a = 0; a < 6; ++a) {
        pf[2 * a]     = *(const u16x8*)(srcs[a] + kh);
        pf[2 * a + 1] = *(const u16x8*)(srcs[a] + kh + 8);
    }

    f32x4 acc[4][4];
#pragma unroll
    for (int i = 0; i < 4; ++i)
#pragma unroll
        for (int j = 0; j < 4; ++j) acc[i][j] = (f32x4){0.f, 0.f, 0.f, 0.f};

    const int fro = (lane & 15) * LR + 8 * (lane >> 4);

    for (int k0 = 0; k0 < K; k0 += KC) {
        __syncthreads();
#pragma unroll
        for (int a = 0; a < 6; ++a) {
            *(u16x8*)&lds[a * 128 * LR + r * LR + kh]     = pf[2 * a];
            *(u16x8*)&lds[a * 128 * LR + r * LR + kh + 8] = pf[2 * a + 1];
        }
        __syncthreads();
        if (k0 + KC < K) {
#pragma unroll
            for (int a = 0; a < 6; ++a) {
                pf[2 * a]     = *(const u16x8*)(srcs[a] + k0 + KC + kh);
                pf[2 * a + 1] = *(const u16x8*)(srcs[a] + k0 + KC + kh + 8);
            }
        }
        bf16x8 af[3][4], bf[3][4];
#pragma unroll
        for (int p = 0; p < 3; ++p)
#pragma unroll
            for (int ti = 0; ti < 4; ++ti) {
                af[p][ti] = *(const bf16x8*)&lds[p * 128 * LR + (wr + ti * 16) * LR + fro];
                bf[p][ti] = *(const bf16x8*)&lds[(3 + p) * 128 * LR + (wc + ti * 16) * LR + fro];
            }
#pragma unroll
        for (int ti = 0; ti < 4; ++ti)
#pragma unroll
            for (int tj = 0; tj < 4; ++tj) {
                f32x4 c = acc[ti][tj];
                c = __builtin_amdgcn_mfma_f32_16x16x32_bf16(af[0][ti], bf[0][tj], c, 0, 0, 0);
                c = __builtin_amdgcn_mfma_f32_16x16x32_bf16(af[0][ti], bf[1][tj], c, 0, 0, 0);
                c = __builtin_amdgcn_mfma_f32_16x16x32_bf16(af[1][ti], bf[0][tj], c, 0, 0, 0);
                c = __builtin_amdgcn_mfma_f32_16x16x32_bf16(af[1][ti], bf[1][tj], c, 0, 0, 0);
                c = __builtin_amdgcn_mfma_f32_16x16x32_bf16(af[0][ti], bf[2][tj], c, 0, 0, 0);
                c = __builtin_amdgcn_mfma_f32_16x16x32_bf16(af[2][ti], bf[0][tj], c, 0, 0, 0);
                acc[ti][tj] = c;
            }
    }

    const int crow = (lane >> 4) * 4;
    const int ccol = lane & 15;
#pragma unroll
    for (int ti = 0; ti < 4; ++ti)
#pragma unroll
        for (int tj = 0; tj < 4; ++tj)
#pragma unroll
            for (int qq = 0; qq < 4; ++qq) {
                const int rr = row0 + wr + ti * 16 + crow + qq;
                const int cc = col0 + wc + tj * 16 + ccol;
                C[(size_t)rr * Nn + cc] = acc[ti][tj][qq];
            }
    if (ct != rt) {
#pragma unroll
        for (int ti = 0; ti < 4; ++ti)
#pragma unroll
            for (int tj = 0; tj < 4; ++tj)
#pragma unroll
                for (int qq = 0; qq < 4; ++qq) {
                    const int rr = row0 + wr + ti * 16 + crow + qq;
                    const int cc = col0 + wc + tj * 16 + ccol;
                    C[(size_t)cc * Nn + rr] = acc[ti][tj][qq];
                }
    }
}

// ---------------------------------------------------------------------------
// Fallback f32 path (r10-proven).
// ---------------------------------------------------------------------------
__global__ __launch_bounds__(128)
void rownorm(const float* __restrict__ in, float* __restrict__ out)
{
    __shared__ float s[2];
    const int r = blockIdx.x, t = threadIdx.x;
    const float4 v = ((const float4*)(in + (size_t)r * 512))[t];
    float ss = v.x * v.x + v.y * v.y + v.z * v.z + v.w * v.w;
#pragma unroll
    for (int off = 32; off; off >>= 1) ss += __shfl_down(ss, off);
    if ((t & 63) == 0) s[t >> 6] = ss;
    __syncthreads();
    const float den = fmaxf(sqrtf(s[0] + s[1]), 1e-12f);
    float4 o;
    o.x = v.x / den; o.y = v.y / den; o.z = v.z / den; o.w = v.w / den;
    ((float4*)(out + (size_t)r * 512))[t] = o;
}

__global__ __launch_bounds__(256)
void gemm_syn(const float* __restrict__ H, float* __restrict__ C, int Nn, int K)
{
    constexpr int KS = 16;
    constexpr int LDT = 132;
    __shared__ float As[KS * LDT];
    __shared__ float Bs[KS * LDT];

    const int q = blockIdx.x;
    int ct = (int)((sqrtf(8.0f * (float)q + 1.0f) - 1.0f) * 0.5f);
    while ((ct + 1) * (ct + 2) / 2 <= q) ++ct;
    while (ct * (ct + 1) / 2 > q) --ct;
    const int rt = q - ct * (ct + 1) / 2;
    const int row0 = rt * 128;
    const int col0 = ct * 128;

    const int t    = threadIdx.x;
    const int tm   = t & 15;
    const int tn   = t >> 4;
    const int lrow = t >> 2;
    const int lk   = (t & 3) << 2;

    const float* Ap0 = H + (size_t)(row0 + lrow)      * K + lk;
    const float* Ap1 = H + (size_t)(row0 + lrow + 64) * K + lk;
    const float* Bp0 = H + (size_t)(col0 + lrow)      * K + lk;
    const float* Bp1 = H + (size_t)(col0 + lrow + 64) * K + lk;

    float4 a0 = *(const float4*)(Ap0);
    float4 a1 = *(const float4*)(Ap1);
    float4 b0 = *(const float4*)(Bp0);
    float4 b1 = *(const float4*)(Bp1);

    float acc[8][8];
#pragma unroll
    for (int i = 0; i < 8; ++i)
#pragma unroll
        for (int j = 0; j < 8; ++j) acc[i][j] = 0.f;

    for (int k0 = 0; k0 < K; k0 += KS) {
        __syncthreads();
        As[(lk + 0) * LDT + lrow] = a0.x;
        As[(lk + 1) * LDT + lrow] = a0.y;
        As[(lk + 2) * LDT + lrow] = a0.z;
        As[(lk + 3) * LDT + lrow] = a0.w;
        As[(lk + 0) * LDT + lrow + 64] = a1.x;
        As[(lk + 1) * LDT + lrow + 64] = a1.y;
        As[(lk + 2) * LDT + lrow + 64] = a1.z;
        As[(lk + 3) * LDT + lrow + 64] = a1.w;
        Bs[(lk + 0) * LDT + lrow] = b0.x;
        Bs[(lk + 1) * LDT + lrow] = b0.y;
        Bs[(lk + 2) * LDT + lrow] = b0.z;
        Bs[(lk + 3) * LDT + lrow] = b0.w;
        Bs[(lk + 0) * LDT + lrow + 64] = b1.x;
        Bs[(lk + 1) * LDT + lrow + 64] = b1.y;
        Bs[(lk + 2) * LDT + lrow + 64] = b1.z;
        Bs[(lk + 3) * LDT + lrow + 64] = b1.w;
        __syncthreads();
        if (k0 + KS < K) {
            a0 = *(const float4*)(Ap0 + k0 + KS);
            a1 = *(const float4*)(Ap1 + k0 + KS);
            b0 = *(const float4*)(Bp0 + k0 + KS);
            b1 = *(const float4*)(Bp1 + k0 + KS);
        }
#pragma unroll
        for (int kk = 0; kk < KS; ++kk) {
            const float4 av0 = *(const float4*)&As[kk * LDT + 4 * tm];
            const float4 av1 = *(const float4*)&As[kk * LDT + 4 * tm + 64];
            const float4 bv0 = *(const float4*)&Bs[kk * LDT + 4 * tn];
            const float4 bv1 = *(const float4*)&Bs[kk * LDT + 4 * tn + 64];
            const float a[8] = {av0.x, av0.y, av0.z, av0.w, av1.x, av1.y, av1.z, av1.w};
            const float bb[8] = {bv0.x, bv0.y, bv0.z, bv0.w, bv1.x, bv1.y, bv1.z, bv1.w};
#pragma unroll
            for (int i = 0; i < 8; ++i)
#pragma unroll
                for (int j = 0; j < 8; ++j)
                    acc[i][j] += a[i] * bb[j];
        }
    }

#pragma unroll
    for (int ih = 0; ih < 2; ++ih)
#pragma unroll
    for (int i2 = 0; i2 < 4; ++i2) {
        const int rr = row0 + ih * 64 + 4 * tm + i2;
        float* Crow = C + (size_t)rr * Nn + col0;
        const int ia = ih * 4 + i2;
        float4 o0 = {acc[ia][0], acc[ia][1], acc[ia][2], acc[ia][3]};
        float4 o1 = {acc[ia][4], acc[ia][5], acc[ia][6], acc[ia][7]};
        *(float4*)(Crow + 4 * tn)      = o0;
        *(float4*)(Crow + 64 + 4 * tn) = o1;
    }
    if (ct != rt) {
#pragma unroll
        for (int jh = 0; jh < 2; ++jh)
#pragma unroll
        for (int j2 = 0; j2 < 4; ++j2) {
            const int rr = col0 + jh * 64 + 4 * tn + j2;
            float* Crow = C + (size_t)rr * Nn + row0;
            const int ja = jh * 4 + j2;
            float4 o0 = {acc[0][ja], acc[1][ja], acc[2][ja], acc[3][ja]};
            float4 o1 = {acc[4][ja], acc[5][ja], acc[6][ja], acc[7][ja]};
            *(float4*)(Crow + 4 * tm)      = o0;
            *(float4*)(Crow + 64 + 4 * tm) = o1;
        }
    }
}

// ---------------------------------------------------------------------------
// In-place per-row top-31 + relu via REGISTER BINARY BIT-DESCENT (exact
// jax.lax.top_k semantics: ties -> lowest index). One block (256 thr)/row.
//
// Atomic-free, histogram-free: each thread holds its 32 mono-keys in VGPRs.
// 32 passes (bit 31..0): cand = X | bit; cnt_ge(cand) via per-thread register
// compares + shfl_xor wave reduce + 4-slot LDS combine (double-buffered by
// bit parity -> 1 barrier/pass, WAR-safe). Invariant cnt_ge(X) >= 31 =>
// final X = exact key of the 31st largest. One extra pass: cgt = cnt_gt(X),
// m = 31 - cgt ties accepted at lowest indices. Replaces topk_radix whose
// pass-0 same-address LDS atomics cost 7e7 conflict-cycles/dispatch (r11).
// ---------------------------------------------------------------------------
__device__ __forceinline__ unsigned monou(unsigned b)
{
    return (b & 0x80000000u) ? ~b : (b | 0x80000000u);
}
__device__ __forceinline__ float unmono(unsigned u)
{
    return __uint_as_float((u & 0x80000000u) ? (u ^ 0x80000000u) : ~u);
}

__global__ __launch_bounds__(256)
void topk_bits(float* __restrict__ sim)
{
    constexpr int NC = 8192;
    constexpr unsigned KSEL = 31;
    __shared__ unsigned wsum[2][4];
    __shared__ int tie_idx[256];
    __shared__ int tie_cnt, sh_thr;

    const int t = threadIdx.x;
    const int lane = t & 63;
    const int wid = t >> 6;
    float* row = sim + (size_t)blockIdx.x * NC;

    if (t == 0) tie_cnt = 0;

    // load 32 elements (8 x uint4, coalesced) into registers as mono keys
    unsigned k[8][4];
#pragma unroll
    for (int j = 0; j < 8; ++j) {
        const uint4 v = *(const uint4*)&row[4 * (t + 256 * j)];
        k[j][0] = monou(v.x); k[j][1] = monou(v.y);
        k[j][2] = monou(v.z); k[j][3] = monou(v.w);
    }

    // 32-bit descent: X ends as the exact key of the 31st largest element
    unsigned X = 0u;
    for (int b = 31; b >= 0; --b) {
        const unsigned cand = X | (1u << b);
        unsigned c = 0;
#pragma unroll
        for (int j = 0; j < 8; ++j)
#pragma unroll
            for (int e = 0; e < 4; ++e)
                c += (k[j][e] >= cand) ? 1u : 0u;
#pragma unroll
        for (int off = 32; off; off >>= 1) c += __shfl_xor(c, off);
        if (lane == 0) wsum[b & 1][wid] = c;
        __syncthreads();                     // slot (b&1) ready; WAR-safe (see note)
        const unsigned tot = wsum[b & 1][0] + wsum[b & 1][1]
                           + wsum[b & 1][2] + wsum[b & 1][3];
        if (tot >= KSEL) X = cand;           // uniform decision across block
    }
    const unsigned uc = X;

    // strict-greater count -> number of cutoff ties to accept
    {
        unsigned c = 0;
#pragma unroll
        for (int j = 0; j < 8; ++j)
#pragma unroll
            for (int e = 0; e < 4; ++e)
                c += (k[j][e] > uc) ? 1u : 0u;
#pragma unroll
        for (int off = 32; off; off >>= 1) c += __shfl_xor(c, off);
        if (lane == 0) wsum[1][wid] = c;     // slot 1: last descent write was slot 0
        __syncthreads();
    }
    const int m = (int)(KSEL - (wsum[1][0] + wsum[1][1] + wsum[1][2] + wsum[1][3]));

    // collect tie indices (== uc), keep the m lowest
#pragma unroll
    for (int j = 0; j < 8; ++j)
#pragma unroll
        for (int e = 0; e < 4; ++e)
            if (k[j][e] == uc) {
                const int p = atomicAdd(&tie_cnt, 1);
                if (p < 256) tie_idx[p] = 4 * (t + 256 * j) + e;
            }
    __syncthreads();
    if (t == 0) {
        int n = tie_cnt < 256 ? tie_cnt : 256;
        for (int a = 1; a < n; ++a) {
            const int key = tie_idx[a];
            int c = a - 1;
            while (c >= 0 && tie_idx[c] > key) { tie_idx[c + 1] = tie_idx[c]; --c; }
            tie_idx[c + 1] = key;
        }
        const int mm = (m <= n ? m : n);
        sh_thr = tie_idx[mm - 1];
    }
    __syncthreads();
    const int tie_thr = sh_thr;

    // writeback straight from registers
#pragma unroll
    for (int j = 0; j < 8; ++j) {
        const int i0 = 4 * (t + 256 * j);
        float4 v;
        v.x = (k[j][0] > uc || (k[j][0] == uc && i0 + 0 <= tie_thr)) ? fmaxf(unmono(k[j][0]), 0.f) : 0.f;
        v.y = (k[j][1] > uc || (k[j][1] == uc && i0 + 1 <= tie_thr)) ? fmaxf(unmono(k[j][1]), 0.f) : 0.f;
        v.z = (k[j][2] > uc || (k[j][2] == uc && i0 + 2 <= tie_thr)) ? fmaxf(unmono(k[j][2]), 0.f) : 0.f;
        v.w = (k[j][3] > uc || (k[j][3] == uc && i0 + 3 <= tie_thr)) ? fmaxf(unmono(k[j][3]), 0.f) : 0.f;
        *(float4*)&row[i0] = v;
    }
}

// ---------------------------------------------------------------------------
extern "C" void kernel_launch(void* const* d_in, const int* in_sizes, int n_in,
                              void* d_out, int out_size, void* d_ws, size_t ws_size,
                              hipStream_t stream)
{
    const float* x = (const float*)d_in[0];
    const float* W = (const float*)d_in[1];
    const float* b = (const float*)d_in[2];
    float* out = (float*)d_out;               // f32 [8192, 8192] = 268 MB

    const int N = 8192, D = 512;
    const int T = N / 128;

    // MLP scratch in d_out (dead before sim GEMM overwrites the full output)
    float* h1 = out;
    float* h2 = out + (size_t)N * D;

    dim3 tb(256);
    gemm_nt<<<dim3(D / 128, N / 128), tb, 0, stream>>>(x,  W,                 b,     h1, N, D, D, 1);
    gemm_nt<<<dim3(D / 128, N / 128), tb, 0, stream>>>(h1, W + (size_t)D * D, b + D, h2, N, D, D, 0);

    const size_t split_bytes = (size_t)3 * N * D * sizeof(unsigned short); // 25.2 MB
    if (ws_size >= split_bytes) {
        unsigned short* Hhi  = (unsigned short*)d_ws;
        unsigned short* Hmid = Hhi  + (size_t)N * D;
        unsigned short* Hlo  = Hmid + (size_t)N * D;
        rownorm_split<<<N, 128, 0, stream>>>(h2, Hhi, Hmid, Hlo);
        gemm_sym_mfma<<<T * (T + 1) / 2, tb, 0, stream>>>(Hhi, Hmid, Hlo, out, N);
    } else {
        float* hn = (float*)d_ws;
        rownorm<<<N, 128, 0, stream>>>(h2, hn);
        gemm_syn<<<T * (T + 1) / 2, tb, 0, stream>>>(hn, out, N, D);
    }
    topk_bits<<<N, tb, 0, stream>>>(out);
}

// Round 14
// 753.908 us; speedup vs baseline: 2.6017x; 1.0059x over previous
//
#include <hip/hip_runtime.h>
#include <hip/hip_bf16.h>

typedef __attribute__((ext_vector_type(8))) short bf16x8;
typedef __attribute__((ext_vector_type(8))) unsigned short u16x8;
typedef __attribute__((ext_vector_type(4))) float f32x4;

// ---------------------------------------------------------------------------
// f32 GEMM "NT", 128x64 tile (MxN), 256 thr, 8x4 micro, K-step 16, register
// prefetch. MLP layers: grid (N/64, M/128) = 512 blocks -> 2 blocks/CU (the
// old 128x128 tile gave 256 blocks = 1/CU, latency-starved). 4+4 row split
// avoids the r9 4-way LDS alias.
// ---------------------------------------------------------------------------
__global__ __launch_bounds__(256)
void gemm_nt64(const float* __restrict__ A, const float* __restrict__ B,
               const float* __restrict__ bias, float* __restrict__ C,
               int M, int N, int K, int do_relu)
{
    constexpr int KS = 16;
    constexpr int LDA = 132;
    constexpr int LDB = 68;
    __shared__ float As[KS * LDA];
    __shared__ float Bs[KS * LDB];

    const int t    = threadIdx.x;
    const int row0 = blockIdx.y * 128;
    const int col0 = blockIdx.x * 64;
    const int tm   = t & 15;
    const int tn   = t >> 4;

    const int arow = t >> 1;        // 0..127
    const int ak   = (t & 1) * 8;   // 0/8
    const int brow = t >> 2;        // 0..63
    const int bk   = (t & 3) * 4;   // 0,4,8,12

    const float* Ap = A + (size_t)(row0 + arow) * K + ak;
    const float* Bp = B + (size_t)(col0 + brow) * K + bk;

    float4 a0 = *(const float4*)(Ap);
    float4 a1 = *(const float4*)(Ap + 4);
    float4 b0 = *(const float4*)(Bp);

    float acc[8][4];
#pragma unroll
    for (int i = 0; i < 8; ++i)
#pragma unroll
        for (int j = 0; j < 4; ++j) acc[i][j] = 0.f;

    for (int k0 = 0; k0 < K; k0 += KS) {
        __syncthreads();
        As[(ak + 0) * LDA + arow] = a0.x;
        As[(ak + 1) * LDA + arow] = a0.y;
        As[(ak + 2) * LDA + arow] = a0.z;
        As[(ak + 3) * LDA + arow] = a0.w;
        As[(ak + 4) * LDA + arow] = a1.x;
        As[(ak + 5) * LDA + arow] = a1.y;
        As[(ak + 6) * LDA + arow] = a1.z;
        As[(ak + 7) * LDA + arow] = a1.w;
        Bs[(bk + 0) * LDB + brow] = b0.x;
        Bs[(bk + 1) * LDB + brow] = b0.y;
        Bs[(bk + 2) * LDB + brow] = b0.z;
        Bs[(bk + 3) * LDB + brow] = b0.w;
        __syncthreads();
        if (k0 + KS < K) {
            a0 = *(const float4*)(Ap + k0 + KS);
            a1 = *(const float4*)(Ap + k0 + KS + 4);
            b0 = *(const float4*)(Bp + k0 + KS);
        }
#pragma unroll
        for (int kk = 0; kk < KS; ++kk) {
            const float4 av0 = *(const float4*)&As[kk * LDA + 4 * tm];
            const float4 av1 = *(const float4*)&As[kk * LDA + 64 + 4 * tm];
            const float4 bv  = *(const float4*)&Bs[kk * LDB + 4 * tn];
            const float a[8] = {av0.x, av0.y, av0.z, av0.w, av1.x, av1.y, av1.z, av1.w};
            const float bb[4] = {bv.x, bv.y, bv.z, bv.w};
#pragma unroll
            for (int i = 0; i < 8; ++i)
#pragma unroll
                for (int j = 0; j < 4; ++j)
                    acc[i][j] += a[i] * bb[j];
        }
    }

#pragma unroll
    for (int ih = 0; ih < 2; ++ih)
#pragma unroll
    for (int i2 = 0; i2 < 4; ++i2) {
        const int r  = row0 + ih * 64 + 4 * tm + i2;
        const int ia = ih * 4 + i2;
        float o[4];
#pragma unroll
        for (int j = 0; j < 4; ++j) o[j] = acc[ia][j];
        if (bias) {
#pragma unroll
            for (int j = 0; j < 4; ++j) o[j] += bias[col0 + 4 * tn + j];
        }
        if (do_relu) {
#pragma unroll
            for (int j = 0; j < 4; ++j) o[j] = fmaxf(o[j], 0.f);
        }
        float4 ov = {o[0], o[1], o[2], o[3]};
        *(float4*)(C + (size_t)r * N + col0 + 4 * tn) = ov;
    }
}

// ---------------------------------------------------------------------------
// Row L2-normalize + bf16x3 SPLIT (hi/mid/lo; resid <= 2^-27 rel).
// ---------------------------------------------------------------------------
__global__ __launch_bounds__(128)
void rownorm_split(const float* __restrict__ in, unsigned short* __restrict__ Hhi,
                   unsigned short* __restrict__ Hmid, unsigned short* __restrict__ Hlo)
{
    __shared__ float s[2];
    const int r = blockIdx.x, t = threadIdx.x;
    const float4 v = ((const float4*)(in + (size_t)r * 512))[t];
    float ss = v.x * v.x + v.y * v.y + v.z * v.z + v.w * v.w;
#pragma unroll
    for (int off = 32; off; off >>= 1) ss += __shfl_down(ss, off);
    if ((t & 63) == 0) s[t >> 6] = ss;
    __syncthreads();
    const float den = fmaxf(sqrtf(s[0] + s[1]), 1e-12f);
    const float f[4] = {v.x / den, v.y / den, v.z / den, v.w / den};
    ushort4 uh, um, ul;
    unsigned short* ph = (unsigned short*)&uh;
    unsigned short* pm = (unsigned short*)&um;
    unsigned short* pl = (unsigned short*)&ul;
#pragma unroll
    for (int j = 0; j < 4; ++j) {
        const __hip_bfloat16 h = __float2bfloat16(f[j]);
        const float fh = __bfloat162float(h);
        const float r1 = f[j] - fh;
        const __hip_bfloat16 m = __float2bfloat16(r1);
        const float fm = __bfloat162float(m);
        const float r2 = r1 - fm;
        const __hip_bfloat16 l = __float2bfloat16(r2);
        ph[j] = *(const unsigned short*)&h;
        pm[j] = *(const unsigned short*)&m;
        pl[j] = *(const unsigned short*)&l;
    }
    const size_t o = (size_t)r * 512 + 4 * t;
    *(ushort4*)(Hhi  + o) = uh;
    *(ushort4*)(Hmid + o) = um;
    *(ushort4*)(Hlo  + o) = ul;
}

// ---------------------------------------------------------------------------
// SYMMETRIC sim GEMM via bf16x3 MFMA, v2:
//  - LDS: 6 tiles of [128 rows][32 bf16], NO pad (64B rows, 8 KB/tile,
//    49.2 KB total -> 3 blocks/CU, was 61.4 KB -> 2). Bank conflicts killed
//    by XOR swizzle byte ^= ((row&7)<<4) applied on BOTH the reg-staged
//    ds_writes and the frag ds_reads (T2 both-sides; r12 counters showed
//    2.56e7 conflict-cycles, write-side dominated: 102M ds_write_b128 with
//    80B-stride 4-way aliasing).
//  - XCD-aware bijective block swizzle (2080 = 8*260) for B-panel L2 reuse.
// Numerics identical to r11/r12 (same 6 products, same accumulation order).
// ---------------------------------------------------------------------------
__global__ __launch_bounds__(256)
void gemm_sym_mfma(const unsigned short* __restrict__ Hhi,
                   const unsigned short* __restrict__ Hmid,
                   const unsigned short* __restrict__ Hlo,
                   float* __restrict__ C, int Nn)
{
    constexpr int K  = 512;
    constexpr int KC = 32;
    __shared__ unsigned short lds[6 * 128 * 32];   // 49152 B, 8192 B per array

    // XCD swizzle: 2080 blocks = 8 XCDs x 260 contiguous logical tiles
    const int q0 = blockIdx.x;
    const int q  = (q0 & 7) * 260 + (q0 >> 3);
    int ct = (int)((sqrtf(8.0f * (float)q + 1.0f) - 1.0f) * 0.5f);
    while ((ct + 1) * (ct + 2) / 2 <= q) ++ct;
    while (ct * (ct + 1) / 2 > q) --ct;
    const int rt = q - ct * (ct + 1) / 2;
    const int row0 = rt * 128;
    const int col0 = ct * 128;

    const int t    = threadIdx.x;
    const int lane = t & 63;
    const int wid  = t >> 6;
    const int wr   = (wid >> 1) * 64;
    const int wc   = (wid & 1) * 64;

    // staging: thread t -> row r = t>>1, k-half kh = (t&1)*16 elems
    const int r   = t >> 1;
    const int kh  = (t & 1) * 16;
    const int wb  = r * 64 + kh * 2;              // linear byte in tile
    const int swW = ((r & 7) << 4);               // write-side XOR
    const unsigned short* srcs[6] = {
        Hhi  + (size_t)(row0 + r) * K, Hmid + (size_t)(row0 + r) * K, Hlo + (size_t)(row0 + r) * K,
        Hhi  + (size_t)(col0 + r) * K, Hmid + (size_t)(col0 + r) * K, Hlo + (size_t)(col0 + r) * K };

    u16x8 pf[12];
#pragma unroll
    for (int a = 0; a < 6; ++a) {
        pf[2 * a]     = *(const u16x8*)(srcs[a] + kh);
        pf[2 * a + 1] = *(const u16x8*)(srcs[a] + kh + 8);
    }

    f32x4 acc[4][4];
#pragma unroll
    for (int i = 0; i < 4; ++i)
#pragma unroll
        for (int j = 0; j < 4; ++j) acc[i][j] = (f32x4){0.f, 0.f, 0.f, 0.f};

    // frag read: row rr = (wr|wc) + ti*16 + (lane&15); byte = rr*64 + (lane>>4)*16
    // rr&7 == lane&7 (wr, ti*16 are multiples of 8) -> constant XOR per lane
    const int g16 = (lane >> 4) << 4;
    const int swR = ((lane & 7) << 4);
    char* ldsb = (char*)lds;

    for (int k0 = 0; k0 < K; k0 += KC) {
        __syncthreads();
#pragma unroll
        for (int a = 0; a < 6; ++a) {
            const int base = a * 8192 + wb;
            *(u16x8*)(ldsb + ((base)      ^ swW)) = pf[2 * a];
            *(u16x8*)(ldsb + ((base + 16) ^ swW)) = pf[2 * a + 1];
        }
        __syncthreads();
        if (k0 + KC < K) {
#pragma unroll
            for (int a = 0; a < 6; ++a) {
                pf[2 * a]     = *(const u16x8*)(srcs[a] + k0 + KC + kh);
                pf[2 * a + 1] = *(const u16x8*)(srcs[a] + k0 + KC + kh + 8);
            }
        }
        bf16x8 af[3][4], bf[3][4];
#pragma unroll
        for (int p = 0; p < 3; ++p)
#pragma unroll
            for (int ti = 0; ti < 4; ++ti) {
                const int rA = wr + ti * 16 + (lane & 15);
                const int rB = wc + ti * 16 + (lane & 15);
                af[p][ti] = *(const bf16x8*)(ldsb + ((p * 8192 + rA * 64 + g16) ^ swR));
                bf[p][ti] = *(const bf16x8*)(ldsb + (((3 + p) * 8192 + rB * 64 + g16) ^ swR));
            }
#pragma unroll
        for (int ti = 0; ti < 4; ++ti)
#pragma unroll
            for (int tj = 0; tj < 4; ++tj) {
                f32x4 c = acc[ti][tj];
                c = __builtin_amdgcn_mfma_f32_16x16x32_bf16(af[0][ti], bf[0][tj], c, 0, 0, 0);
                c = __builtin_amdgcn_mfma_f32_16x16x32_bf16(af[0][ti], bf[1][tj], c, 0, 0, 0);
                c = __builtin_amdgcn_mfma_f32_16x16x32_bf16(af[1][ti], bf[0][tj], c, 0, 0, 0);
                c = __builtin_amdgcn_mfma_f32_16x16x32_bf16(af[1][ti], bf[1][tj], c, 0, 0, 0);
                c = __builtin_amdgcn_mfma_f32_16x16x32_bf16(af[0][ti], bf[2][tj], c, 0, 0, 0);
                c = __builtin_amdgcn_mfma_f32_16x16x32_bf16(af[2][ti], bf[0][tj], c, 0, 0, 0);
                acc[ti][tj] = c;
            }
    }

    const int crow = (lane >> 4) * 4;
    const int ccol = lane & 15;
#pragma unroll
    for (int ti = 0; ti < 4; ++ti)
#pragma unroll
        for (int tj = 0; tj < 4; ++tj)
#pragma unroll
            for (int qq = 0; qq < 4; ++qq) {
                const int rr = row0 + wr + ti * 16 + crow + qq;
                const int cc = col0 + wc + tj * 16 + ccol;
                C[(size_t)rr * Nn + cc] = acc[ti][tj][qq];
            }
    if (ct != rt) {
#pragma unroll
        for (int ti = 0; ti < 4; ++ti)
#pragma unroll
            for (int tj = 0; tj < 4; ++tj)
#pragma unroll
                for (int qq = 0; qq < 4; ++qq) {
                    const int rr = row0 + wr + ti * 16 + crow + qq;
                    const int cc = col0 + wc + tj * 16 + ccol;
                    C[(size_t)cc * Nn + rr] = acc[ti][tj][qq];
                }
    }
}

// ---------------------------------------------------------------------------
// Fallback f32 path (r10-proven) if ws is too small for splits.
// ---------------------------------------------------------------------------
__global__ __launch_bounds__(128)
void rownorm(const float* __restrict__ in, float* __restrict__ out)
{
    __shared__ float s[2];
    const int r = blockIdx.x, t = threadIdx.x;
    const float4 v = ((const float4*)(in + (size_t)r * 512))[t];
    float ss = v.x * v.x + v.y * v.y + v.z * v.z + v.w * v.w;
#pragma unroll
    for (int off = 32; off; off >>= 1) ss += __shfl_down(ss, off);
    if ((t & 63) == 0) s[t >> 6] = ss;
    __syncthreads();
    const float den = fmaxf(sqrtf(s[0] + s[1]), 1e-12f);
    float4 o;
    o.x = v.x / den; o.y = v.y / den; o.z = v.z / den; o.w = v.w / den;
    ((float4*)(out + (size_t)r * 512))[t] = o;
}

__global__ __launch_bounds__(256)
void gemm_syn(const float* __restrict__ H, float* __restrict__ C, int Nn, int K)
{
    constexpr int KS = 16;
    constexpr int LDT = 132;
    __shared__ float As[KS * LDT];
    __shared__ float Bs[KS * LDT];

    const int q = blockIdx.x;
    int ct = (int)((sqrtf(8.0f * (float)q + 1.0f) - 1.0f) * 0.5f);
    while ((ct + 1) * (ct + 2) / 2 <= q) ++ct;
    while (ct * (ct + 1) / 2 > q) --ct;
    const int rt = q - ct * (ct + 1) / 2;
    const int row0 = rt * 128;
    const int col0 = ct * 128;

    const int t    = threadIdx.x;
    const int tm   = t & 15;
    const int tn   = t >> 4;
    const int lrow = t >> 2;
    const int lk   = (t & 3) << 2;

    const float* Ap0 = H + (size_t)(row0 + lrow)      * K + lk;
    const float* Ap1 = H + (size_t)(row0 + lrow + 64) * K + lk;
    const float* Bp0 = H + (size_t)(col0 + lrow)      * K + lk;
    const float* Bp1 = H + (size_t)(col0 + lrow + 64) * K + lk;

    float4 a0 = *(const float4*)(Ap0);
    float4 a1 = *(const float4*)(Ap1);
    float4 b0 = *(const float4*)(Bp0);
    float4 b1 = *(const float4*)(Bp1);

    float acc[8][8];
#pragma unroll
    for (int i = 0; i < 8; ++i)
#pragma unroll
        for (int j = 0; j < 8; ++j) acc[i][j] = 0.f;

    for (int k0 = 0; k0 < K; k0 += KS) {
        __syncthreads();
        As[(lk + 0) * LDT + lrow] = a0.x;
        As[(lk + 1) * LDT + lrow] = a0.y;
        As[(lk + 2) * LDT + lrow] = a0.z;
        As[(lk + 3) * LDT + lrow] = a0.w;
        As[(lk + 0) * LDT + lrow + 64] = a1.x;
        As[(lk + 1) * LDT + lrow + 64] = a1.y;
        As[(lk + 2) * LDT + lrow + 64] = a1.z;
        As[(lk + 3) * LDT + lrow + 64] = a1.w;
        Bs[(lk + 0) * LDT + lrow] = b0.x;
        Bs[(lk + 1) * LDT + lrow] = b0.y;
        Bs[(lk + 2) * LDT + lrow] = b0.z;
        Bs[(lk + 3) * LDT + lrow] = b0.w;
        Bs[(lk + 0) * LDT + lrow + 64] = b1.x;
        Bs[(lk + 1) * LDT + lrow + 64] = b1.y;
        Bs[(lk + 2) * LDT + lrow + 64] = b1.z;
        Bs[(lk + 3) * LDT + lrow + 64] = b1.w;
        __syncthreads();
        if (k0 + KS < K) {
            a0 = *(const float4*)(Ap0 + k0 + KS);
            a1 = *(const float4*)(Ap1 + k0 + KS);
            b0 = *(const float4*)(Bp0 + k0 + KS);
            b1 = *(const float4*)(Bp1 + k0 + KS);
        }
#pragma unroll
        for (int kk = 0; kk < KS; ++kk) {
            const float4 av0 = *(const float4*)&As[kk * LDT + 4 * tm];
            const float4 av1 = *(const float4*)&As[kk * LDT + 4 * tm + 64];
            const float4 bv0 = *(const float4*)&Bs[kk * LDT + 4 * tn];
            const float4 bv1 = *(const float4*)&Bs[kk * LDT + 4 * tn + 64];
            const float a[8] = {av0.x, av0.y, av0.z, av0.w, av1.x, av1.y, av1.z, av1.w};
            const float bb[8] = {bv0.x, bv0.y, bv0.z, bv0.w, bv1.x, bv1.y, bv1.z, bv1.w};
#pragma unroll
            for (int i = 0; i < 8; ++i)
#pragma unroll
                for (int j = 0; j < 8; ++j)
                    acc[i][j] += a[i] * bb[j];
        }
    }

#pragma unroll
    for (int ih = 0; ih < 2; ++ih)
#pragma unroll
    for (int i2 = 0; i2 < 4; ++i2) {
        const int rr = row0 + ih * 64 + 4 * tm + i2;
        float* Crow = C + (size_t)rr * Nn + col0;
        const int ia = ih * 4 + i2;
        float4 o0 = {acc[ia][0], acc[ia][1], acc[ia][2], acc[ia][3]};
        float4 o1 = {acc[ia][4], acc[ia][5], acc[ia][6], acc[ia][7]};
        *(float4*)(Crow + 4 * tn)      = o0;
        *(float4*)(Crow + 64 + 4 * tn) = o1;
    }
    if (ct != rt) {
#pragma unroll
        for (int jh = 0; jh < 2; ++jh)
#pragma unroll
        for (int j2 = 0; j2 < 4; ++j2) {
            const int rr = col0 + jh * 64 + 4 * tn + j2;
            float* Crow = C + (size_t)rr * Nn + row0;
            const int ja = jh * 4 + j2;
            float4 o0 = {acc[0][ja], acc[1][ja], acc[2][ja], acc[3][ja]};
            float4 o1 = {acc[4][ja], acc[5][ja], acc[6][ja], acc[7][ja]};
            *(float4*)(Crow + 4 * tm)      = o0;
            *(float4*)(Crow + 64 + 4 * tm) = o1;
        }
    }
}

// ---------------------------------------------------------------------------
// In-place per-row top-31 + relu via REGISTER BINARY BIT-DESCENT
// (r12-proven; exact jax.lax.top_k tie semantics).
// ---------------------------------------------------------------------------
__device__ __forceinline__ unsigned monou(unsigned b)
{
    return (b & 0x80000000u) ? ~b : (b | 0x80000000u);
}
__device__ __forceinline__ float unmono(unsigned u)
{
    return __uint_as_float((u & 0x80000000u) ? (u ^ 0x80000000u) : ~u);
}

__global__ __launch_bounds__(256)
void topk_bits(float* __restrict__ sim)
{
    constexpr int NC = 8192;
    constexpr unsigned KSEL = 31;
    __shared__ unsigned wsum[2][4];
    __shared__ int tie_idx[256];
    __shared__ int tie_cnt, sh_thr;

    const int t = threadIdx.x;
    const int lane = t & 63;
    const int wid = t >> 6;
    float* row = sim + (size_t)blockIdx.x * NC;

    if (t == 0) tie_cnt = 0;

    unsigned k[8][4];
#pragma unroll
    for (int j = 0; j < 8; ++j) {
        const uint4 v = *(const uint4*)&row[4 * (t + 256 * j)];
        k[j][0] = monou(v.x); k[j][1] = monou(v.y);
        k[j][2] = monou(v.z); k[j][3] = monou(v.w);
    }

    unsigned X = 0u;
    for (int b = 31; b >= 0; --b) {
        const unsigned cand = X | (1u << b);
        unsigned c = 0;
#pragma unroll
        for (int j = 0; j < 8; ++j)
#pragma unroll
            for (int e = 0; e < 4; ++e)
                c += (k[j][e] >= cand) ? 1u : 0u;
#pragma unroll
        for (int off = 32; off; off >>= 1) c += __shfl_xor(c, off);
        if (lane == 0) wsum[b & 1][wid] = c;
        __syncthreads();
        const unsigned tot = wsum[b & 1][0] + wsum[b & 1][1]
                           + wsum[b & 1][2] + wsum[b & 1][3];
        if (tot >= KSEL) X = cand;
    }
    const unsigned uc = X;

    {
        unsigned c = 0;
#pragma unroll
        for (int j = 0; j < 8; ++j)
#pragma unroll
            for (int e = 0; e < 4; ++e)
                c += (k[j][e] > uc) ? 1u : 0u;
#pragma unroll
        for (int off = 32; off; off >>= 1) c += __shfl_xor(c, off);
        if (lane == 0) wsum[1][wid] = c;
        __syncthreads();
    }
    const int m = (int)(KSEL - (wsum[1][0] + wsum[1][1] + wsum[1][2] + wsum[1][3]));

#pragma unroll
    for (int j = 0; j < 8; ++j)
#pragma unroll
        for (int e = 0; e < 4; ++e)
            if (k[j][e] == uc) {
                const int p = atomicAdd(&tie_cnt, 1);
                if (p < 256) tie_idx[p] = 4 * (t + 256 * j) + e;
            }
    __syncthreads();
    if (t == 0) {
        int n = tie_cnt < 256 ? tie_cnt : 256;
        for (int a = 1; a < n; ++a) {
            const int key = tie_idx[a];
            int c = a - 1;
            while (c >= 0 && tie_idx[c] > key) { tie_idx[c + 1] = tie_idx[c]; --c; }
            tie_idx[c + 1] = key;
        }
        const int mm = (m <= n ? m : n);
        sh_thr = tie_idx[mm - 1];
    }
    __syncthreads();
    const int tie_thr = sh_thr;

#pragma unroll
    for (int j = 0; j < 8; ++j) {
        const int i0 = 4 * (t + 256 * j);
        float4 v;
        v.x = (k[j][0] > uc || (k[j][0] == uc && i0 + 0 <= tie_thr)) ? fmaxf(unmono(k[j][0]), 0.f) : 0.f;
        v.y = (k[j][1] > uc || (k[j][1] == uc && i0 + 1 <= tie_thr)) ? fmaxf(unmono(k[j][1]), 0.f) : 0.f;
        v.z = (k[j][2] > uc || (k[j][2] == uc && i0 + 2 <= tie_thr)) ? fmaxf(unmono(k[j][2]), 0.f) : 0.f;
        v.w = (k[j][3] > uc || (k[j][3] == uc && i0 + 3 <= tie_thr)) ? fmaxf(unmono(k[j][3]), 0.f) : 0.f;
        *(float4*)&row[i0] = v;
    }
}

// ---------------------------------------------------------------------------
extern "C" void kernel_launch(void* const* d_in, const int* in_sizes, int n_in,
                              void* d_out, int out_size, void* d_ws, size_t ws_size,
                              hipStream_t stream)
{
    const float* x = (const float*)d_in[0];
    const float* W = (const float*)d_in[1];
    const float* b = (const float*)d_in[2];
    float* out = (float*)d_out;               // f32 [8192, 8192] = 268 MB

    const int N = 8192, D = 512;
    const int T = N / 128;

    // MLP scratch in d_out (dead before sim GEMM overwrites the full output)
    float* h1 = out;
    float* h2 = out + (size_t)N * D;

    dim3 tb(256);
    gemm_nt64<<<dim3(D / 64, N / 128), tb, 0, stream>>>(x,  W,                 b,     h1, N, D, D, 1);
    gemm_nt64<<<dim3(D / 64, N / 128), tb, 0, stream>>>(h1, W + (size_t)D * D, b + D, h2, N, D, D, 0);

    const size_t split_bytes = (size_t)3 * N * D * sizeof(unsigned short); // 25.2 MB
    if (ws_size >= split_bytes) {
        unsigned short* Hhi  = (unsigned short*)d_ws;
        unsigned short* Hmid = Hhi  + (size_t)N * D;
        unsigned short* Hlo  = Hmid + (size_t)N * D;
        rownorm_split<<<N, 128, 0, stream>>>(h2, Hhi, Hmid, Hlo);
        gemm_sym_mfma<<<T * (T + 1) / 2, tb, 0, stream>>>(Hhi, Hmid, Hlo, out, N);
    } else {
        float* hn = (float*)d_ws;
        rownorm<<<N, 128, 0, stream>>>(h2, hn);
        gemm_syn<<<T * (T + 1) / 2, tb, 0, stream>>>(hn, out, N, D);
    }
    topk_bits<<<N, tb, 0, stream>>>(out);
}